// Round 1
// baseline (1874.776 us; speedup 1.0000x reference)
//
#include <hip/hip_runtime.h>
#include <hip/hip_bf16.h>
#include <hip/hip_fp16.h>

// FastMambaBlock: in_proj GEMM -> split -> depthwise conv1d -> x_proj GEMM
// -> dt_proj GEMM + softplus -> selective scan (+ u*D, silu gating)
// -> out_proj GEMM. All GEMMs: f16 MFMA 16x16x32, 128x128 tile, BK=32,
// global_load_lds staging (m97 structure).

typedef _Float16 f16;
typedef __attribute__((ext_vector_type(4))) float f32x4;
typedef __attribute__((ext_vector_type(4))) _Float16 f16x4;
typedef __attribute__((ext_vector_type(8))) _Float16 f16x8;

#define AS1C(p) ((const __attribute__((address_space(1))) void*)(p))
#define AS3(p)  ((__attribute__((address_space(3))) void*)(p))

#define D_MODEL 1024
#define D_INNER 2048
#define LSEQ    2048
#define NB      4

// ---------------- conversion kernels ----------------
__global__ void cvt_f32_to_f16(const float* __restrict__ in, f16* __restrict__ out, int n4) {
  int i = blockIdx.x * blockDim.x + threadIdx.x;
  if (i >= n4) return;
  f32x4 v = *(const f32x4*)(in + (size_t)i * 4);
  f16x4 o;
  o[0] = (f16)v[0]; o[1] = (f16)v[1]; o[2] = (f16)v[2]; o[3] = (f16)v[3];
  *(f16x4*)(out + (size_t)i * 4) = o;
}

// x_proj_w [160][2048] f32 -> padded [256][2048] f16 (rows 160..255 = 0)
__global__ void cvt_pad_xproj(const float* __restrict__ in, f16* __restrict__ out) {
  int i = blockIdx.x * blockDim.x + threadIdx.x;  // one per 4 elems; total 131072
  int idx = i << 2;
  int row = idx >> 11;
  f16x4 o;
  if (row < 160) {
    f32x4 v = *(const f32x4*)(in + idx);
    o[0] = (f16)v[0]; o[1] = (f16)v[1]; o[2] = (f16)v[2]; o[3] = (f16)v[3];
  } else {
    o[0] = (f16)0.f; o[1] = (f16)0.f; o[2] = (f16)0.f; o[3] = (f16)0.f;
  }
  *(f16x4*)(out + idx) = o;
}

// ---------------- GEMM: C[M][N] = A[M][K] @ W[N][K]^T (+bias, epilogue) ----
// EPI 0: +bias, split-store f16 -> O0 (n<2048: xc_raw), O1 (n>=2048: res)
// EPI 1: no bias, f16 store to O0 with ld=ldo, guard n<NV   (x_proj)
// EPI 2: +bias, softplus, f16 store ld=ldo                  (dt_proj)
// EPI 3: +bias, f32 store ld=ldo                            (out_proj)
template<int EPI>
__global__ __launch_bounds__(256) void gemm_f16(
    const f16* __restrict__ A, int lda,
    const f16* __restrict__ Bw, int K,
    const float* __restrict__ bias,
    void* __restrict__ O0, void* __restrict__ O1,
    int NV, int ldo)
{
  __shared__ f16 lA[128 * 32];
  __shared__ f16 lB[128 * 32];
  const int tid  = threadIdx.x;
  const int lane = tid & 63;
  const int wid  = tid >> 6;
  const int wr = wid >> 1, wc = wid & 1;
  const int tm = blockIdx.y * 128, tn = blockIdx.x * 128;

  f32x4 acc[4][4] = {};

  // staging: 8 chunks of 1KB per tile; wave stages chunks {2*wid, 2*wid+1}
  const int i4 = lane >> 2;          // row within chunk (0..15)
  const int k8 = (lane & 3) << 3;    // k offset (f16 elems)
  const int ca = wid << 1;
  const f16* Abase = A  + (size_t)(tm + ca * 16 + i4) * lda + k8;
  const f16* Bbase = Bw + (size_t)(tn + ca * 16 + i4) * K   + k8;

  const int nKT = K >> 5;
  for (int kt = 0; kt < nKT; ++kt) {
    const int ko = kt << 5;
    __syncthreads();  // previous tile fully consumed
    __builtin_amdgcn_global_load_lds(AS1C(Abase + ko),                    AS3(lA + ca * 512),       16, 0, 0);
    __builtin_amdgcn_global_load_lds(AS1C(Abase + (size_t)16 * lda + ko), AS3(lA + ca * 512 + 512), 16, 0, 0);
    __builtin_amdgcn_global_load_lds(AS1C(Bbase + ko),                    AS3(lB + ca * 512),       16, 0, 0);
    __builtin_amdgcn_global_load_lds(AS1C(Bbase + (size_t)16 * K + ko),   AS3(lB + ca * 512 + 512), 16, 0, 0);
    __syncthreads();  // implies s_waitcnt vmcnt(0) -> staging complete

    const int ro = lane & 15;
    const int kf = (lane >> 4) << 3;  // k-group of 8 per 16-lane group
    f16x8 af[4], bf[4];
#pragma unroll
    for (int mi = 0; mi < 4; ++mi)
      af[mi] = *(const f16x8*)(lA + (wr * 64 + mi * 16 + ro) * 32 + kf);
#pragma unroll
    for (int nj = 0; nj < 4; ++nj)
      bf[nj] = *(const f16x8*)(lB + (wc * 64 + nj * 16 + ro) * 32 + kf);
#pragma unroll
    for (int mi = 0; mi < 4; ++mi)
#pragma unroll
      for (int nj = 0; nj < 4; ++nj)
        acc[mi][nj] = __builtin_amdgcn_mfma_f32_16x16x32_f16(af[mi], bf[nj], acc[mi][nj], 0, 0, 0);
  }

  // epilogue: D row = (lane>>4)*4 + j, col = lane&15
#pragma unroll
  for (int mi = 0; mi < 4; ++mi) {
    const int rb = tm + wr * 64 + mi * 16 + ((lane >> 4) << 2);
#pragma unroll
    for (int nj = 0; nj < 4; ++nj) {
      const int gn = tn + wc * 64 + nj * 16 + (lane & 15);
      if (gn >= NV) continue;
      float bv = 0.f;
      if constexpr (EPI != 1) bv = bias[gn];
#pragma unroll
      for (int j = 0; j < 4; ++j) {
        const float v = acc[mi][nj][j] + bv;
        const size_t row = (size_t)(rb + j);
        if constexpr (EPI == 0) {
          if (gn < 2048) ((f16*)O0)[row * 2048 + gn] = (f16)v;
          else           ((f16*)O1)[row * 2048 + (gn - 2048)] = (f16)v;
        } else if constexpr (EPI == 1) {
          ((f16*)O0)[row * (size_t)ldo + gn] = (f16)v;
        } else if constexpr (EPI == 2) {
          const float sp = (v > 20.f) ? v : log1pf(__expf(v));
          ((f16*)O0)[row * (size_t)ldo + gn] = (f16)sp;
        } else {
          ((float*)O0)[row * (size_t)ldo + gn] = v;
        }
      }
    }
  }
}

// ---------------- depthwise conv1d (k=4, pad 1 left / 2 right) ------------
__global__ __launch_bounds__(256) void conv1d_kernel(
    const f16* __restrict__ xin, const float* __restrict__ w,
    const float* __restrict__ cb, f16* __restrict__ xout)
{
  const int d0  = threadIdx.x << 3;        // 8 channels per thread
  const int bid = blockIdx.x;
  const int b   = bid >> 8;                // 256 blocks per batch
  const int l0  = (bid & 255) << 3;        // 8 timesteps per block
  float wv[4][8];
#pragma unroll
  for (int q = 0; q < 8; ++q) {
    f32x4 t = *(const f32x4*)(w + (size_t)(d0 + q) * 4);
    wv[0][q] = t[0]; wv[1][q] = t[1]; wv[2][q] = t[2]; wv[3][q] = t[3];
  }
  float bv[8];
  *(f32x4*)bv       = *(const f32x4*)(cb + d0);
  *(f32x4*)(bv + 4) = *(const f32x4*)(cb + d0 + 4);
  const size_t base = (size_t)b * LSEQ * D_INNER;
  for (int lt = l0; lt < l0 + 8; ++lt) {
    float acc[8];
#pragma unroll
    for (int q = 0; q < 8; ++q) acc[q] = bv[q];
#pragma unroll
    for (int j = 0; j < 4; ++j) {
      const int li = lt + j - 1;
      if (li < 0 || li >= LSEQ) continue;
      f16x8 v = *(const f16x8*)(xin + base + (size_t)li * D_INNER + d0);
#pragma unroll
      for (int q = 0; q < 8; ++q) acc[q] += wv[j][q] * (float)v[q];
    }
    f16x8 o;
#pragma unroll
    for (int q = 0; q < 8; ++q) o[q] = (f16)acc[q];
    *(f16x8*)(xout + base + (size_t)lt * D_INNER + d0) = o;
  }
}

// ---------------- selective scan + gating ---------------------------------
// lane = n + 16*dsub; each 16-lane group owns one (b,d); h_n per lane.
// y = sum_n h_n*C_n (shfl_xor reduce) + u*D; out = y*silu(res) as f16.
__global__ __launch_bounds__(256) void scan_kernel(
    const f16* __restrict__ delta, const f16* __restrict__ u,
    const f16* __restrict__ xdbl, const f16* __restrict__ res,
    const float* __restrict__ A_log, const float* __restrict__ Dp,
    f16* __restrict__ yg)
{
  const int bid  = blockIdx.x;           // 512 = 4 b * 128 d-chunks
  const int b    = bid >> 7;
  const int d0   = (bid & 127) << 4;     // 16 d per block
  const int lane = threadIdx.x & 63;
  const int wid  = threadIdx.x >> 6;
  const int n    = lane & 15;
  const int dsub = lane >> 4;
  const int d    = d0 + wid * 4 + dsub;

  const float An = -expf(A_log[(size_t)d * 16 + n]);
  const float Dd = Dp[d];
  float h = 0.f;
  const size_t rowBase = (size_t)b * LSEQ;

  for (int t = 0; t < LSEQ; ++t) {
    const size_t r = rowBase + t;
    const float dlt = (float)delta[r * D_INNER + d];
    const float uu  = (float)u[r * D_INNER + d];
    const float Bn  = (float)xdbl[r * 160 + 128 + n];
    const float Cn  = (float)xdbl[r * 160 + 144 + n];
    const float dA  = __expf(dlt * An);
    h = dA * h + (dlt * uu) * Bn;
    float yp = h * Cn;
    yp += __shfl_xor(yp, 1);
    yp += __shfl_xor(yp, 2);
    yp += __shfl_xor(yp, 4);
    yp += __shfl_xor(yp, 8);
    if (n == 0) {
      const float y  = yp + uu * Dd;
      const float rr = (float)res[r * D_INNER + d];
      const float sil = rr / (1.f + __expf(-rr));
      yg[r * D_INNER + d] = (f16)(y * sil);
    }
  }
}

// ---------------- launch ----------------------------------------------------
extern "C" void kernel_launch(void* const* d_in, const int* in_sizes, int n_in,
                              void* d_out, int out_size, void* d_ws, size_t ws_size,
                              hipStream_t stream) {
  const float* x      = (const float*)d_in[0];
  const float* w_in_f = (const float*)d_in[1];
  const float* b_in   = (const float*)d_in[2];
  const float* conv_w = (const float*)d_in[3];
  const float* conv_b = (const float*)d_in[4];
  const float* w_xp_f = (const float*)d_in[5];
  const float* w_dt_f = (const float*)d_in[6];
  const float* b_dt   = (const float*)d_in[7];
  const float* A_log  = (const float*)d_in[8];
  const float* Dp     = (const float*)d_in[9];
  const float* w_ot_f = (const float*)d_in[10];
  const float* b_ot   = (const float*)d_in[11];

  char* ws = (char*)d_ws;
  size_t o = 0;
  auto alloc = [&](size_t bytes) -> char* {
    char* p = ws + o; o += (bytes + 255) & ~(size_t)255; return p;
  };
  f16* xf    = (f16*)alloc(16777216);   // x in f16           [8192][1024]
  f16* w_in  = (f16*)alloc(8388608);    // in_proj_w f16      [4096][1024]
  f16* w_xp  = (f16*)alloc(1048576);    // x_proj_w padded    [256][2048]
  f16* w_dt  = (f16*)alloc(524288);     // dt_proj_w f16      [2048][128]
  f16* w_ot  = (f16*)alloc(4194304);    // out_proj_w f16     [1024][2048]
  f16* xcr   = (f16*)alloc(33554432);   // xc_raw; reused as y_gated
  f16* res   = (f16*)alloc(33554432);   // res gate           [8192][2048]
  f16* xc    = (f16*)alloc(33554432);   // post-conv          [8192][2048]
  f16* xdbl  = (f16*)alloc(2621440);    // x_dbl              [8192][160]
  f16* delta = (f16*)alloc(33554432);   // softplus output    [8192][2048]

  dim3 blk(256);
  cvt_f32_to_f16<<<8192, blk, 0, stream>>>(x,      xf,   2097152);
  cvt_f32_to_f16<<<4096, blk, 0, stream>>>(w_in_f, w_in, 1048576);
  cvt_pad_xproj <<<512,  blk, 0, stream>>>(w_xp_f, w_xp);
  cvt_f32_to_f16<<<256,  blk, 0, stream>>>(w_dt_f, w_dt, 65536);
  cvt_f32_to_f16<<<2048, blk, 0, stream>>>(w_ot_f, w_ot, 524288);

  // in_proj: [8192,1024] @ [4096,1024]^T -> split xc_raw / res
  gemm_f16<0><<<dim3(32, 64), blk, 0, stream>>>(xf, 1024, w_in, 1024, b_in,
                                                xcr, res, 4096, 2048);
  // depthwise conv
  conv1d_kernel<<<1024, blk, 0, stream>>>(xcr, conv_w, conv_b, xc);
  // x_proj: [8192,2048] @ [160(pad 256),2048]^T -> xdbl (ld 160)
  gemm_f16<1><<<dim3(2, 64), blk, 0, stream>>>(xc, 2048, w_xp, 2048, nullptr,
                                               xdbl, nullptr, 160, 160);
  // dt_proj: [8192,128](ld 160) @ [2048,128]^T + b -> softplus -> delta
  gemm_f16<2><<<dim3(16, 64), blk, 0, stream>>>(xdbl, 160, w_dt, 128, b_dt,
                                                delta, nullptr, 2048, 2048);
  // selective scan + u*D + silu(res) gating -> y_gated (reuse xcr)
  scan_kernel<<<512, blk, 0, stream>>>(delta, xc, xdbl, res, A_log, Dp, xcr);
  // out_proj: [8192,2048] @ [1024,2048]^T + b -> d_out f32
  gemm_f16<3><<<dim3(8, 64), blk, 0, stream>>>(xcr, 2048, w_ot, 2048, b_ot,
                                               d_out, nullptr, 1024, 1024);
}

// Round 2
// 1874.001 us; speedup vs baseline: 1.0004x; 1.0004x over previous
//
#include <hip/hip_runtime.h>
#include <hip/hip_bf16.h>
#include <hip/hip_fp16.h>

// FastMambaBlock: in_proj GEMM -> split -> depthwise conv1d -> x_proj GEMM
// -> dt_proj GEMM + softplus -> selective scan (+ u*D, silu gating)
// -> out_proj GEMM. All GEMMs: f16 MFMA 16x16x32, 128x128 tile, BK=32,
// global_load_lds staging (m97 structure).

typedef _Float16 f16;
typedef __attribute__((ext_vector_type(4))) float f32x4;
typedef __attribute__((ext_vector_type(4))) _Float16 f16x4;
typedef __attribute__((ext_vector_type(8))) _Float16 f16x8;

#define AS1C(p) ((const __attribute__((address_space(1))) void*)(p))
#define AS3(p)  ((__attribute__((address_space(3))) void*)(p))

#define D_MODEL 1024
#define D_INNER 2048
#define LSEQ    2048
#define NB      4

// ---------------- conversion kernels ----------------
__global__ void cvt_f32_to_f16(const float* __restrict__ in, f16* __restrict__ out, int n4) {
  int i = blockIdx.x * blockDim.x + threadIdx.x;
  if (i >= n4) return;
  f32x4 v = *(const f32x4*)(in + (size_t)i * 4);
  f16x4 o;
  o[0] = (f16)v[0]; o[1] = (f16)v[1]; o[2] = (f16)v[2]; o[3] = (f16)v[3];
  *(f16x4*)(out + (size_t)i * 4) = o;
}

// x_proj_w [160][2048] f32 -> padded [256][2048] f16 (rows 160..255 = 0)
__global__ void cvt_pad_xproj(const float* __restrict__ in, f16* __restrict__ out) {
  int i = blockIdx.x * blockDim.x + threadIdx.x;  // one per 4 elems; total 131072
  int idx = i << 2;
  int row = idx >> 11;
  f16x4 o;
  if (row < 160) {
    f32x4 v = *(const f32x4*)(in + idx);
    o[0] = (f16)v[0]; o[1] = (f16)v[1]; o[2] = (f16)v[2]; o[3] = (f16)v[3];
  } else {
    o[0] = (f16)0.f; o[1] = (f16)0.f; o[2] = (f16)0.f; o[3] = (f16)0.f;
  }
  *(f16x4*)(out + idx) = o;
}

// ---------------- GEMM: C[M][N] = A[M][K] @ W[N][K]^T (+bias, epilogue) ----
// EPI 0: +bias, split-store f16 -> O0 (n<2048: xc_raw), O1 (n>=2048: res)
// EPI 1: no bias, f16 store to O0 with ld=ldo, guard n<NV   (x_proj)
// EPI 2: +bias, softplus, f16 store ld=ldo                  (dt_proj)
// EPI 3: +bias, f32 store ld=ldo                            (out_proj)
template<int EPI>
__global__ __launch_bounds__(256) void gemm_f16(
    const f16* __restrict__ A, int lda,
    const f16* __restrict__ Bw, int K,
    const float* __restrict__ bias,
    void* __restrict__ O0, void* __restrict__ O1,
    int NV, int ldo)
{
  __shared__ f16 lA[128 * 32];
  __shared__ f16 lB[128 * 32];
  const int tid  = threadIdx.x;
  const int lane = tid & 63;
  const int wid  = tid >> 6;
  const int wr = wid >> 1, wc = wid & 1;
  const int tm = blockIdx.y * 128, tn = blockIdx.x * 128;

  f32x4 acc[4][4] = {};

  // staging: 8 chunks of 1KB per tile; wave stages chunks {2*wid, 2*wid+1}
  const int i4 = lane >> 2;          // row within chunk (0..15)
  const int k8 = (lane & 3) << 3;    // k offset (f16 elems)
  const int ca = wid << 1;
  const f16* Abase = A  + (size_t)(tm + ca * 16 + i4) * lda + k8;
  const f16* Bbase = Bw + (size_t)(tn + ca * 16 + i4) * K   + k8;

  const int nKT = K >> 5;
  for (int kt = 0; kt < nKT; ++kt) {
    const int ko = kt << 5;
    __syncthreads();  // previous tile fully consumed
    __builtin_amdgcn_global_load_lds(AS1C(Abase + ko),                    AS3(lA + ca * 512),       16, 0, 0);
    __builtin_amdgcn_global_load_lds(AS1C(Abase + (size_t)16 * lda + ko), AS3(lA + ca * 512 + 512), 16, 0, 0);
    __builtin_amdgcn_global_load_lds(AS1C(Bbase + ko),                    AS3(lB + ca * 512),       16, 0, 0);
    __builtin_amdgcn_global_load_lds(AS1C(Bbase + (size_t)16 * K + ko),   AS3(lB + ca * 512 + 512), 16, 0, 0);
    __syncthreads();  // implies s_waitcnt vmcnt(0) -> staging complete

    const int ro = lane & 15;
    const int kf = (lane >> 4) << 3;  // k-group of 8 per 16-lane group
    f16x8 af[4], bf[4];
#pragma unroll
    for (int mi = 0; mi < 4; ++mi)
      af[mi] = *(const f16x8*)(lA + (wr * 64 + mi * 16 + ro) * 32 + kf);
#pragma unroll
    for (int nj = 0; nj < 4; ++nj)
      bf[nj] = *(const f16x8*)(lB + (wc * 64 + nj * 16 + ro) * 32 + kf);
#pragma unroll
    for (int mi = 0; mi < 4; ++mi)
#pragma unroll
      for (int nj = 0; nj < 4; ++nj)
        acc[mi][nj] = __builtin_amdgcn_mfma_f32_16x16x32_f16(af[mi], bf[nj], acc[mi][nj], 0, 0, 0);
  }

  // epilogue: D row = (lane>>4)*4 + j, col = lane&15
#pragma unroll
  for (int mi = 0; mi < 4; ++mi) {
    const int rb = tm + wr * 64 + mi * 16 + ((lane >> 4) << 2);
#pragma unroll
    for (int nj = 0; nj < 4; ++nj) {
      const int gn = tn + wc * 64 + nj * 16 + (lane & 15);
      if (gn >= NV) continue;
      float bv = 0.f;
      if constexpr (EPI != 1) bv = bias[gn];
#pragma unroll
      for (int j = 0; j < 4; ++j) {
        const float v = acc[mi][nj][j] + bv;
        const size_t row = (size_t)(rb + j);
        if constexpr (EPI == 0) {
          if (gn < 2048) ((f16*)O0)[row * 2048 + gn] = (f16)v;
          else           ((f16*)O1)[row * 2048 + (gn - 2048)] = (f16)v;
        } else if constexpr (EPI == 1) {
          ((f16*)O0)[row * (size_t)ldo + gn] = (f16)v;
        } else if constexpr (EPI == 2) {
          const float sp = (v > 20.f) ? v : log1pf(__expf(v));
          ((f16*)O0)[row * (size_t)ldo + gn] = (f16)sp;
        } else {
          ((float*)O0)[row * (size_t)ldo + gn] = v;
        }
      }
    }
  }
}

// ---------------- depthwise conv1d (k=4, pad 1 left / 2 right) ------------
__global__ __launch_bounds__(256) void conv1d_kernel(
    const f16* __restrict__ xin, const float* __restrict__ w,
    const float* __restrict__ cb, f16* __restrict__ xout)
{
  const int d0  = threadIdx.x << 3;        // 8 channels per thread
  const int bid = blockIdx.x;
  const int b   = bid >> 8;                // 256 blocks per batch
  const int l0  = (bid & 255) << 3;        // 8 timesteps per block
  float wv[4][8];
#pragma unroll
  for (int q = 0; q < 8; ++q) {
    f32x4 t = *(const f32x4*)(w + (size_t)(d0 + q) * 4);
    wv[0][q] = t[0]; wv[1][q] = t[1]; wv[2][q] = t[2]; wv[3][q] = t[3];
  }
  float bv[8];
  *(f32x4*)bv       = *(const f32x4*)(cb + d0);
  *(f32x4*)(bv + 4) = *(const f32x4*)(cb + d0 + 4);
  const size_t base = (size_t)b * LSEQ * D_INNER;
  for (int lt = l0; lt < l0 + 8; ++lt) {
    float acc[8];
#pragma unroll
    for (int q = 0; q < 8; ++q) acc[q] = bv[q];
#pragma unroll
    for (int j = 0; j < 4; ++j) {
      const int li = lt + j - 1;
      if (li < 0 || li >= LSEQ) continue;
      f16x8 v = *(const f16x8*)(xin + base + (size_t)li * D_INNER + d0);
#pragma unroll
      for (int q = 0; q < 8; ++q) acc[q] += wv[j][q] * (float)v[q];
    }
    f16x8 o;
#pragma unroll
    for (int q = 0; q < 8; ++q) o[q] = (f16)acc[q];
    *(f16x8*)(xout + base + (size_t)lt * D_INNER + d0) = o;
  }
}

// ---------------- selective scan + gating ---------------------------------
// lane = n + 16*dsub; each 16-lane group owns one (b,d); h_n per lane.
// y = sum_n h_n*C_n (shfl_xor reduce) + u*D; out = y*silu(res) as f16.
__global__ __launch_bounds__(256) void scan_kernel(
    const f16* __restrict__ delta, const f16* __restrict__ u,
    const f16* __restrict__ xdbl, const f16* __restrict__ res,
    const float* __restrict__ A_log, const float* __restrict__ Dp,
    f16* __restrict__ yg)
{
  const int bid  = blockIdx.x;           // 512 = 4 b * 128 d-chunks
  const int b    = bid >> 7;
  const int d0   = (bid & 127) << 4;     // 16 d per block
  const int lane = threadIdx.x & 63;
  const int wid  = threadIdx.x >> 6;
  const int n    = lane & 15;
  const int dsub = lane >> 4;
  const int d    = d0 + wid * 4 + dsub;

  const float An = -expf(A_log[(size_t)d * 16 + n]);
  const float Dd = Dp[d];
  float h = 0.f;
  const size_t rowBase = (size_t)b * LSEQ;

  for (int t = 0; t < LSEQ; ++t) {
    const size_t r = rowBase + t;
    const float dlt = (float)delta[r * D_INNER + d];
    const float uu  = (float)u[r * D_INNER + d];
    const float Bn  = (float)xdbl[r * 160 + 128 + n];
    const float Cn  = (float)xdbl[r * 160 + 144 + n];
    const float dA  = __expf(dlt * An);
    h = dA * h + (dlt * uu) * Bn;
    float yp = h * Cn;
    yp += __shfl_xor(yp, 1);
    yp += __shfl_xor(yp, 2);
    yp += __shfl_xor(yp, 4);
    yp += __shfl_xor(yp, 8);
    if (n == 0) {
      const float y  = yp + uu * Dd;
      const float rr = (float)res[r * D_INNER + d];
      const float sil = rr / (1.f + __expf(-rr));
      yg[r * D_INNER + d] = (f16)(y * sil);
    }
  }
}

// ---------------- launch ----------------------------------------------------
extern "C" void kernel_launch(void* const* d_in, const int* in_sizes, int n_in,
                              void* d_out, int out_size, void* d_ws, size_t ws_size,
                              hipStream_t stream) {
  const float* x      = (const float*)d_in[0];
  const float* w_in_f = (const float*)d_in[1];
  const float* b_in   = (const float*)d_in[2];
  const float* conv_w = (const float*)d_in[3];
  const float* conv_b = (const float*)d_in[4];
  const float* w_xp_f = (const float*)d_in[5];
  const float* w_dt_f = (const float*)d_in[6];
  const float* b_dt   = (const float*)d_in[7];
  const float* A_log  = (const float*)d_in[8];
  const float* Dp     = (const float*)d_in[9];
  const float* w_ot_f = (const float*)d_in[10];
  const float* b_ot   = (const float*)d_in[11];

  char* ws = (char*)d_ws;
  size_t o = 0;
  auto alloc = [&](size_t bytes) -> char* {
    char* p = ws + o; o += (bytes + 255) & ~(size_t)255; return p;
  };
  f16* xf    = (f16*)alloc(16777216);   // x in f16           [8192][1024]
  f16* w_in  = (f16*)alloc(8388608);    // in_proj_w f16      [4096][1024]
  f16* w_xp  = (f16*)alloc(1048576);    // x_proj_w padded    [256][2048]
  f16* w_dt  = (f16*)alloc(524288);     // dt_proj_w f16      [2048][128]
  f16* w_ot  = (f16*)alloc(4194304);    // out_proj_w f16     [1024][2048]
  f16* xcr   = (f16*)alloc(33554432);   // xc_raw; reused as y_gated
  f16* res   = (f16*)alloc(33554432);   // res gate           [8192][2048]
  f16* xc    = (f16*)alloc(33554432);   // post-conv          [8192][2048]
  f16* xdbl  = (f16*)alloc(2621440);    // x_dbl              [8192][160]
  f16* delta = (f16*)alloc(33554432);   // softplus output    [8192][2048]

  dim3 blk(256);
  cvt_f32_to_f16<<<8192, blk, 0, stream>>>(x,      xf,   2097152);
  cvt_f32_to_f16<<<4096, blk, 0, stream>>>(w_in_f, w_in, 1048576);
  cvt_pad_xproj <<<512,  blk, 0, stream>>>(w_xp_f, w_xp);
  cvt_f32_to_f16<<<256,  blk, 0, stream>>>(w_dt_f, w_dt, 65536);
  cvt_f32_to_f16<<<2048, blk, 0, stream>>>(w_ot_f, w_ot, 524288);

  // in_proj: [8192,1024] @ [4096,1024]^T -> split xc_raw / res
  gemm_f16<0><<<dim3(32, 64), blk, 0, stream>>>(xf, 1024, w_in, 1024, b_in,
                                                xcr, res, 4096, 2048);
  // depthwise conv
  conv1d_kernel<<<1024, blk, 0, stream>>>(xcr, conv_w, conv_b, xc);
  // x_proj: [8192,2048] @ [160(pad 256),2048]^T -> xdbl (ld 160)
  gemm_f16<1><<<dim3(2, 64), blk, 0, stream>>>(xc, 2048, w_xp, 2048, nullptr,
                                               xdbl, nullptr, 160, 160);
  // dt_proj: [8192,128](ld 160) @ [2048,128]^T + b -> softplus -> delta
  gemm_f16<2><<<dim3(16, 64), blk, 0, stream>>>(xdbl, 160, w_dt, 128, b_dt,
                                                delta, nullptr, 2048, 2048);
  // selective scan + u*D + silu(res) gating -> y_gated (reuse xcr)
  scan_kernel<<<512, blk, 0, stream>>>(delta, xc, xdbl, res, A_log, Dp, xcr);
  // out_proj: [8192,2048] @ [1024,2048]^T + b -> d_out f32
  gemm_f16<3><<<dim3(8, 64), blk, 0, stream>>>(xcr, 2048, w_ot, 2048, b_ot,
                                               d_out, nullptr, 1024, 1024);
}

// Round 3
// 1873.583 us; speedup vs baseline: 1.0006x; 1.0002x over previous
//
#include <hip/hip_runtime.h>
#include <hip/hip_bf16.h>
#include <hip/hip_fp16.h>

// FastMambaBlock: in_proj GEMM -> split -> depthwise conv1d -> x_proj GEMM
// -> dt_proj GEMM + softplus -> selective scan (+ u*D, silu gating)
// -> out_proj GEMM. All GEMMs: f16 MFMA 16x16x32, 128x128 tile, BK=32,
// global_load_lds staging (m97 structure).

typedef _Float16 f16;
typedef __attribute__((ext_vector_type(4))) float f32x4;
typedef __attribute__((ext_vector_type(4))) _Float16 f16x4;
typedef __attribute__((ext_vector_type(8))) _Float16 f16x8;

#define AS1C(p) ((const __attribute__((address_space(1))) void*)(p))
#define AS3(p)  ((__attribute__((address_space(3))) void*)(p))

#define D_MODEL 1024
#define D_INNER 2048
#define LSEQ    2048
#define NB      4

// ---------------- conversion kernels ----------------
__global__ void cvt_f32_to_f16(const float* __restrict__ in, f16* __restrict__ out, int n4) {
  int i = blockIdx.x * blockDim.x + threadIdx.x;
  if (i >= n4) return;
  f32x4 v = *(const f32x4*)(in + (size_t)i * 4);
  f16x4 o;
  o[0] = (f16)v[0]; o[1] = (f16)v[1]; o[2] = (f16)v[2]; o[3] = (f16)v[3];
  *(f16x4*)(out + (size_t)i * 4) = o;
}

// x_proj_w [160][2048] f32 -> padded [256][2048] f16 (rows 160..255 = 0)
__global__ void cvt_pad_xproj(const float* __restrict__ in, f16* __restrict__ out) {
  int i = blockIdx.x * blockDim.x + threadIdx.x;  // one per 4 elems; total 131072
  int idx = i << 2;
  int row = idx >> 11;
  f16x4 o;
  if (row < 160) {
    f32x4 v = *(const f32x4*)(in + idx);
    o[0] = (f16)v[0]; o[1] = (f16)v[1]; o[2] = (f16)v[2]; o[3] = (f16)v[3];
  } else {
    o[0] = (f16)0.f; o[1] = (f16)0.f; o[2] = (f16)0.f; o[3] = (f16)0.f;
  }
  *(f16x4*)(out + idx) = o;
}

// ---------------- GEMM: C[M][N] = A[M][K] @ W[N][K]^T (+bias, epilogue) ----
// EPI 0: +bias, split-store f16 -> O0 (n<2048: xc_raw), O1 (n>=2048: res)
// EPI 1: no bias, f16 store to O0 with ld=ldo, guard n<NV   (x_proj)
// EPI 2: +bias, softplus, f16 store ld=ldo                  (dt_proj)
// EPI 3: +bias, f32 store ld=ldo                            (out_proj)
template<int EPI>
__global__ __launch_bounds__(256) void gemm_f16(
    const f16* __restrict__ A, int lda,
    const f16* __restrict__ Bw, int K,
    const float* __restrict__ bias,
    void* __restrict__ O0, void* __restrict__ O1,
    int NV, int ldo)
{
  __shared__ f16 lA[128 * 32];
  __shared__ f16 lB[128 * 32];
  const int tid  = threadIdx.x;
  const int lane = tid & 63;
  const int wid  = tid >> 6;
  const int wr = wid >> 1, wc = wid & 1;
  const int tm = blockIdx.y * 128, tn = blockIdx.x * 128;

  f32x4 acc[4][4] = {};

  // staging: 8 chunks of 1KB per tile; wave stages chunks {2*wid, 2*wid+1}
  const int i4 = lane >> 2;          // row within chunk (0..15)
  const int k8 = (lane & 3) << 3;    // k offset (f16 elems)
  const int ca = wid << 1;
  const f16* Abase = A  + (size_t)(tm + ca * 16 + i4) * lda + k8;
  const f16* Bbase = Bw + (size_t)(tn + ca * 16 + i4) * K   + k8;

  const int nKT = K >> 5;
  for (int kt = 0; kt < nKT; ++kt) {
    const int ko = kt << 5;
    __syncthreads();  // previous tile fully consumed
    __builtin_amdgcn_global_load_lds(AS1C(Abase + ko),                    AS3(lA + ca * 512),       16, 0, 0);
    __builtin_amdgcn_global_load_lds(AS1C(Abase + (size_t)16 * lda + ko), AS3(lA + ca * 512 + 512), 16, 0, 0);
    __builtin_amdgcn_global_load_lds(AS1C(Bbase + ko),                    AS3(lB + ca * 512),       16, 0, 0);
    __builtin_amdgcn_global_load_lds(AS1C(Bbase + (size_t)16 * K + ko),   AS3(lB + ca * 512 + 512), 16, 0, 0);
    __syncthreads();  // implies s_waitcnt vmcnt(0) -> staging complete

    const int ro = lane & 15;
    const int kf = (lane >> 4) << 3;  // k-group of 8 per 16-lane group
    f16x8 af[4], bf[4];
#pragma unroll
    for (int mi = 0; mi < 4; ++mi)
      af[mi] = *(const f16x8*)(lA + (wr * 64 + mi * 16 + ro) * 32 + kf);
#pragma unroll
    for (int nj = 0; nj < 4; ++nj)
      bf[nj] = *(const f16x8*)(lB + (wc * 64 + nj * 16 + ro) * 32 + kf);
#pragma unroll
    for (int mi = 0; mi < 4; ++mi)
#pragma unroll
      for (int nj = 0; nj < 4; ++nj)
        acc[mi][nj] = __builtin_amdgcn_mfma_f32_16x16x32_f16(af[mi], bf[nj], acc[mi][nj], 0, 0, 0);
  }

  // epilogue: D row = (lane>>4)*4 + j, col = lane&15
#pragma unroll
  for (int mi = 0; mi < 4; ++mi) {
    const int rb = tm + wr * 64 + mi * 16 + ((lane >> 4) << 2);
#pragma unroll
    for (int nj = 0; nj < 4; ++nj) {
      const int gn = tn + wc * 64 + nj * 16 + (lane & 15);
      if (gn >= NV) continue;
      float bv = 0.f;
      if constexpr (EPI != 1) bv = bias[gn];
#pragma unroll
      for (int j = 0; j < 4; ++j) {
        const float v = acc[mi][nj][j] + bv;
        const size_t row = (size_t)(rb + j);
        if constexpr (EPI == 0) {
          if (gn < 2048) ((f16*)O0)[row * 2048 + gn] = (f16)v;
          else           ((f16*)O1)[row * 2048 + (gn - 2048)] = (f16)v;
        } else if constexpr (EPI == 1) {
          ((f16*)O0)[row * (size_t)ldo + gn] = (f16)v;
        } else if constexpr (EPI == 2) {
          const float sp = (v > 20.f) ? v : log1pf(__expf(v));
          ((f16*)O0)[row * (size_t)ldo + gn] = (f16)sp;
        } else {
          ((float*)O0)[row * (size_t)ldo + gn] = v;
        }
      }
    }
  }
}

// ---------------- depthwise conv1d (k=4, pad 1 left / 2 right) ------------
__global__ __launch_bounds__(256) void conv1d_kernel(
    const f16* __restrict__ xin, const float* __restrict__ w,
    const float* __restrict__ cb, f16* __restrict__ xout)
{
  const int d0  = threadIdx.x << 3;        // 8 channels per thread
  const int bid = blockIdx.x;
  const int b   = bid >> 8;                // 256 blocks per batch
  const int l0  = (bid & 255) << 3;        // 8 timesteps per block
  float wv[4][8];
#pragma unroll
  for (int q = 0; q < 8; ++q) {
    f32x4 t = *(const f32x4*)(w + (size_t)(d0 + q) * 4);
    wv[0][q] = t[0]; wv[1][q] = t[1]; wv[2][q] = t[2]; wv[3][q] = t[3];
  }
  float bv[8];
  *(f32x4*)bv       = *(const f32x4*)(cb + d0);
  *(f32x4*)(bv + 4) = *(const f32x4*)(cb + d0 + 4);
  const size_t base = (size_t)b * LSEQ * D_INNER;
  for (int lt = l0; lt < l0 + 8; ++lt) {
    float acc[8];
#pragma unroll
    for (int q = 0; q < 8; ++q) acc[q] = bv[q];
#pragma unroll
    for (int j = 0; j < 4; ++j) {
      const int li = lt + j - 1;
      if (li < 0 || li >= LSEQ) continue;
      f16x8 v = *(const f16x8*)(xin + base + (size_t)li * D_INNER + d0);
#pragma unroll
      for (int q = 0; q < 8; ++q) acc[q] += wv[j][q] * (float)v[q];
    }
    f16x8 o;
#pragma unroll
    for (int q = 0; q < 8; ++q) o[q] = (f16)acc[q];
    *(f16x8*)(xout + base + (size_t)lt * D_INNER + d0) = o;
  }
}

// ---------------- selective scan + gating ---------------------------------
// lane = n + 16*dsub; each 16-lane group owns one (b,d); h_n per lane.
// y = sum_n h_n*C_n (shfl_xor reduce) + u*D; out = y*silu(res) as f16.
__global__ __launch_bounds__(256) void scan_kernel(
    const f16* __restrict__ delta, const f16* __restrict__ u,
    const f16* __restrict__ xdbl, const f16* __restrict__ res,
    const float* __restrict__ A_log, const float* __restrict__ Dp,
    f16* __restrict__ yg)
{
  const int bid  = blockIdx.x;           // 512 = 4 b * 128 d-chunks
  const int b    = bid >> 7;
  const int d0   = (bid & 127) << 4;     // 16 d per block
  const int lane = threadIdx.x & 63;
  const int wid  = threadIdx.x >> 6;
  const int n    = lane & 15;
  const int dsub = lane >> 4;
  const int d    = d0 + wid * 4 + dsub;

  const float An = -expf(A_log[(size_t)d * 16 + n]);
  const float Dd = Dp[d];
  float h = 0.f;
  const size_t rowBase = (size_t)b * LSEQ;

  for (int t = 0; t < LSEQ; ++t) {
    const size_t r = rowBase + t;
    const float dlt = (float)delta[r * D_INNER + d];
    const float uu  = (float)u[r * D_INNER + d];
    const float Bn  = (float)xdbl[r * 160 + 128 + n];
    const float Cn  = (float)xdbl[r * 160 + 144 + n];
    const float dA  = __expf(dlt * An);
    h = dA * h + (dlt * uu) * Bn;
    float yp = h * Cn;
    yp += __shfl_xor(yp, 1);
    yp += __shfl_xor(yp, 2);
    yp += __shfl_xor(yp, 4);
    yp += __shfl_xor(yp, 8);
    if (n == 0) {
      const float y  = yp + uu * Dd;
      const float rr = (float)res[r * D_INNER + d];
      const float sil = rr / (1.f + __expf(-rr));
      yg[r * D_INNER + d] = (f16)(y * sil);
    }
  }
}

// ---------------- launch ----------------------------------------------------
extern "C" void kernel_launch(void* const* d_in, const int* in_sizes, int n_in,
                              void* d_out, int out_size, void* d_ws, size_t ws_size,
                              hipStream_t stream) {
  const float* x      = (const float*)d_in[0];
  const float* w_in_f = (const float*)d_in[1];
  const float* b_in   = (const float*)d_in[2];
  const float* conv_w = (const float*)d_in[3];
  const float* conv_b = (const float*)d_in[4];
  const float* w_xp_f = (const float*)d_in[5];
  const float* w_dt_f = (const float*)d_in[6];
  const float* b_dt   = (const float*)d_in[7];
  const float* A_log  = (const float*)d_in[8];
  const float* Dp     = (const float*)d_in[9];
  const float* w_ot_f = (const float*)d_in[10];
  const float* b_ot   = (const float*)d_in[11];

  char* ws = (char*)d_ws;
  size_t o = 0;
  auto alloc = [&](size_t bytes) -> char* {
    char* p = ws + o; o += (bytes + 255) & ~(size_t)255; return p;
  };
  f16* xf    = (f16*)alloc(16777216);   // x in f16           [8192][1024]
  f16* w_in  = (f16*)alloc(8388608);    // in_proj_w f16      [4096][1024]
  f16* w_xp  = (f16*)alloc(1048576);    // x_proj_w padded    [256][2048]
  f16* w_dt  = (f16*)alloc(524288);     // dt_proj_w f16      [2048][128]
  f16* w_ot  = (f16*)alloc(4194304);    // out_proj_w f16     [1024][2048]
  f16* xcr   = (f16*)alloc(33554432);   // xc_raw; reused as y_gated
  f16* res   = (f16*)alloc(33554432);   // res gate           [8192][2048]
  f16* xc    = (f16*)alloc(33554432);   // post-conv          [8192][2048]
  f16* xdbl  = (f16*)alloc(2621440);    // x_dbl              [8192][160]
  f16* delta = (f16*)alloc(33554432);   // softplus output    [8192][2048]

  dim3 blk(256);
  cvt_f32_to_f16<<<8192, blk, 0, stream>>>(x,      xf,   2097152);
  cvt_f32_to_f16<<<4096, blk, 0, stream>>>(w_in_f, w_in, 1048576);
  cvt_pad_xproj <<<512,  blk, 0, stream>>>(w_xp_f, w_xp);
  cvt_f32_to_f16<<<256,  blk, 0, stream>>>(w_dt_f, w_dt, 65536);
  cvt_f32_to_f16<<<2048, blk, 0, stream>>>(w_ot_f, w_ot, 524288);

  // in_proj: [8192,1024] @ [4096,1024]^T -> split xc_raw / res
  gemm_f16<0><<<dim3(32, 64), blk, 0, stream>>>(xf, 1024, w_in, 1024, b_in,
                                                xcr, res, 4096, 2048);
  // depthwise conv
  conv1d_kernel<<<1024, blk, 0, stream>>>(xcr, conv_w, conv_b, xc);
  // x_proj: [8192,2048] @ [160(pad 256),2048]^T -> xdbl (ld 160)
  gemm_f16<1><<<dim3(2, 64), blk, 0, stream>>>(xc, 2048, w_xp, 2048, nullptr,
                                               xdbl, nullptr, 160, 160);
  // dt_proj: [8192,128](ld 160) @ [2048,128]^T + b -> softplus -> delta
  gemm_f16<2><<<dim3(16, 64), blk, 0, stream>>>(xdbl, 160, w_dt, 128, b_dt,
                                                delta, nullptr, 2048, 2048);
  // selective scan + u*D + silu(res) gating -> y_gated (reuse xcr)
  scan_kernel<<<512, blk, 0, stream>>>(delta, xc, xdbl, res, A_log, Dp, xcr);
  // out_proj: [8192,2048] @ [1024,2048]^T + b -> d_out f32
  gemm_f16<3><<<dim3(8, 64), blk, 0, stream>>>(xcr, 2048, w_ot, 2048, b_ot,
                                               d_out, nullptr, 1024, 1024);
}

// Round 4
// 1871.992 us; speedup vs baseline: 1.0015x; 1.0008x over previous
//
#include <hip/hip_runtime.h>
#include <hip/hip_bf16.h>
#include <hip/hip_fp16.h>

// FastMambaBlock: in_proj GEMM -> split -> depthwise conv1d -> x_proj GEMM
// -> dt_proj GEMM + softplus -> selective scan (+ u*D, silu gating)
// -> out_proj GEMM. All GEMMs: f16 MFMA 16x16x32, 128x128 tile, BK=32,
// global_load_lds staging (m97 structure).

typedef _Float16 f16;
typedef __attribute__((ext_vector_type(4))) float f32x4;
typedef __attribute__((ext_vector_type(4))) _Float16 f16x4;
typedef __attribute__((ext_vector_type(8))) _Float16 f16x8;

#define AS1C(p) ((const __attribute__((address_space(1))) void*)(p))
#define AS3(p)  ((__attribute__((address_space(3))) void*)(p))

#define D_MODEL 1024
#define D_INNER 2048
#define LSEQ    2048
#define NB      4

// ---------------- conversion kernels ----------------
__global__ void cvt_f32_to_f16(const float* __restrict__ in, f16* __restrict__ out, int n4) {
  int i = blockIdx.x * blockDim.x + threadIdx.x;
  if (i >= n4) return;
  f32x4 v = *(const f32x4*)(in + (size_t)i * 4);
  f16x4 o;
  o[0] = (f16)v[0]; o[1] = (f16)v[1]; o[2] = (f16)v[2]; o[3] = (f16)v[3];
  *(f16x4*)(out + (size_t)i * 4) = o;
}

// x_proj_w [160][2048] f32 -> padded [256][2048] f16 (rows 160..255 = 0)
__global__ void cvt_pad_xproj(const float* __restrict__ in, f16* __restrict__ out) {
  int i = blockIdx.x * blockDim.x + threadIdx.x;  // one per 4 elems; total 131072
  int idx = i << 2;
  int row = idx >> 11;
  f16x4 o;
  if (row < 160) {
    f32x4 v = *(const f32x4*)(in + idx);
    o[0] = (f16)v[0]; o[1] = (f16)v[1]; o[2] = (f16)v[2]; o[3] = (f16)v[3];
  } else {
    o[0] = (f16)0.f; o[1] = (f16)0.f; o[2] = (f16)0.f; o[3] = (f16)0.f;
  }
  *(f16x4*)(out + idx) = o;
}

// ---------------- GEMM: C[M][N] = A[M][K] @ W[N][K]^T (+bias, epilogue) ----
// EPI 0: +bias, split-store f16 -> O0 (n<2048: xc_raw), O1 (n>=2048: res)
// EPI 1: no bias, f16 store to O0 with ld=ldo, guard n<NV   (x_proj)
// EPI 2: +bias, softplus, f16 store ld=ldo                  (dt_proj)
// EPI 3: +bias, f32 store ld=ldo                            (out_proj)
template<int EPI>
__global__ __launch_bounds__(256) void gemm_f16(
    const f16* __restrict__ A, int lda,
    const f16* __restrict__ Bw, int K,
    const float* __restrict__ bias,
    void* __restrict__ O0, void* __restrict__ O1,
    int NV, int ldo)
{
  __shared__ f16 lA[128 * 32];
  __shared__ f16 lB[128 * 32];
  const int tid  = threadIdx.x;
  const int lane = tid & 63;
  const int wid  = tid >> 6;
  const int wr = wid >> 1, wc = wid & 1;
  const int tm = blockIdx.y * 128, tn = blockIdx.x * 128;

  f32x4 acc[4][4] = {};

  // staging: 8 chunks of 1KB per tile; wave stages chunks {2*wid, 2*wid+1}
  const int i4 = lane >> 2;          // row within chunk (0..15)
  const int k8 = (lane & 3) << 3;    // k offset (f16 elems)
  const int ca = wid << 1;
  const f16* Abase = A  + (size_t)(tm + ca * 16 + i4) * lda + k8;
  const f16* Bbase = Bw + (size_t)(tn + ca * 16 + i4) * K   + k8;

  const int nKT = K >> 5;
  for (int kt = 0; kt < nKT; ++kt) {
    const int ko = kt << 5;
    __syncthreads();  // previous tile fully consumed
    __builtin_amdgcn_global_load_lds(AS1C(Abase + ko),                    AS3(lA + ca * 512),       16, 0, 0);
    __builtin_amdgcn_global_load_lds(AS1C(Abase + (size_t)16 * lda + ko), AS3(lA + ca * 512 + 512), 16, 0, 0);
    __builtin_amdgcn_global_load_lds(AS1C(Bbase + ko),                    AS3(lB + ca * 512),       16, 0, 0);
    __builtin_amdgcn_global_load_lds(AS1C(Bbase + (size_t)16 * K + ko),   AS3(lB + ca * 512 + 512), 16, 0, 0);
    __syncthreads();  // implies s_waitcnt vmcnt(0) -> staging complete

    const int ro = lane & 15;
    const int kf = (lane >> 4) << 3;  // k-group of 8 per 16-lane group
    f16x8 af[4], bf[4];
#pragma unroll
    for (int mi = 0; mi < 4; ++mi)
      af[mi] = *(const f16x8*)(lA + (wr * 64 + mi * 16 + ro) * 32 + kf);
#pragma unroll
    for (int nj = 0; nj < 4; ++nj)
      bf[nj] = *(const f16x8*)(lB + (wc * 64 + nj * 16 + ro) * 32 + kf);
#pragma unroll
    for (int mi = 0; mi < 4; ++mi)
#pragma unroll
      for (int nj = 0; nj < 4; ++nj)
        acc[mi][nj] = __builtin_amdgcn_mfma_f32_16x16x32_f16(af[mi], bf[nj], acc[mi][nj], 0, 0, 0);
  }

  // epilogue: D row = (lane>>4)*4 + j, col = lane&15
#pragma unroll
  for (int mi = 0; mi < 4; ++mi) {
    const int rb = tm + wr * 64 + mi * 16 + ((lane >> 4) << 2);
#pragma unroll
    for (int nj = 0; nj < 4; ++nj) {
      const int gn = tn + wc * 64 + nj * 16 + (lane & 15);
      if (gn >= NV) continue;
      float bv = 0.f;
      if constexpr (EPI != 1) bv = bias[gn];
#pragma unroll
      for (int j = 0; j < 4; ++j) {
        const float v = acc[mi][nj][j] + bv;
        const size_t row = (size_t)(rb + j);
        if constexpr (EPI == 0) {
          if (gn < 2048) ((f16*)O0)[row * 2048 + gn] = (f16)v;
          else           ((f16*)O1)[row * 2048 + (gn - 2048)] = (f16)v;
        } else if constexpr (EPI == 1) {
          ((f16*)O0)[row * (size_t)ldo + gn] = (f16)v;
        } else if constexpr (EPI == 2) {
          const float sp = (v > 20.f) ? v : log1pf(__expf(v));
          ((f16*)O0)[row * (size_t)ldo + gn] = (f16)sp;
        } else {
          ((float*)O0)[row * (size_t)ldo + gn] = v;
        }
      }
    }
  }
}

// ---------------- depthwise conv1d (k=4, pad 1 left / 2 right) ------------
__global__ __launch_bounds__(256) void conv1d_kernel(
    const f16* __restrict__ xin, const float* __restrict__ w,
    const float* __restrict__ cb, f16* __restrict__ xout)
{
  const int d0  = threadIdx.x << 3;        // 8 channels per thread
  const int bid = blockIdx.x;
  const int b   = bid >> 8;                // 256 blocks per batch
  const int l0  = (bid & 255) << 3;        // 8 timesteps per block
  float wv[4][8];
#pragma unroll
  for (int q = 0; q < 8; ++q) {
    f32x4 t = *(const f32x4*)(w + (size_t)(d0 + q) * 4);
    wv[0][q] = t[0]; wv[1][q] = t[1]; wv[2][q] = t[2]; wv[3][q] = t[3];
  }
  float bv[8];
  *(f32x4*)bv       = *(const f32x4*)(cb + d0);
  *(f32x4*)(bv + 4) = *(const f32x4*)(cb + d0 + 4);
  const size_t base = (size_t)b * LSEQ * D_INNER;
  for (int lt = l0; lt < l0 + 8; ++lt) {
    float acc[8];
#pragma unroll
    for (int q = 0; q < 8; ++q) acc[q] = bv[q];
#pragma unroll
    for (int j = 0; j < 4; ++j) {
      const int li = lt + j - 1;
      if (li < 0 || li >= LSEQ) continue;
      f16x8 v = *(const f16x8*)(xin + base + (size_t)li * D_INNER + d0);
#pragma unroll
      for (int q = 0; q < 8; ++q) acc[q] += wv[j][q] * (float)v[q];
    }
    f16x8 o;
#pragma unroll
    for (int q = 0; q < 8; ++q) o[q] = (f16)acc[q];
    *(f16x8*)(xout + base + (size_t)lt * D_INNER + d0) = o;
  }
}

// ---------------- selective scan + gating ---------------------------------
// lane = n + 16*dsub; each 16-lane group owns one (b,d); h_n per lane.
// y = sum_n h_n*C_n (shfl_xor reduce) + u*D; out = y*silu(res) as f16.
__global__ __launch_bounds__(256) void scan_kernel(
    const f16* __restrict__ delta, const f16* __restrict__ u,
    const f16* __restrict__ xdbl, const f16* __restrict__ res,
    const float* __restrict__ A_log, const float* __restrict__ Dp,
    f16* __restrict__ yg)
{
  const int bid  = blockIdx.x;           // 512 = 4 b * 128 d-chunks
  const int b    = bid >> 7;
  const int d0   = (bid & 127) << 4;     // 16 d per block
  const int lane = threadIdx.x & 63;
  const int wid  = threadIdx.x >> 6;
  const int n    = lane & 15;
  const int dsub = lane >> 4;
  const int d    = d0 + wid * 4 + dsub;

  const float An = -expf(A_log[(size_t)d * 16 + n]);
  const float Dd = Dp[d];
  float h = 0.f;
  const size_t rowBase = (size_t)b * LSEQ;

  for (int t = 0; t < LSEQ; ++t) {
    const size_t r = rowBase + t;
    const float dlt = (float)delta[r * D_INNER + d];
    const float uu  = (float)u[r * D_INNER + d];
    const float Bn  = (float)xdbl[r * 160 + 128 + n];
    const float Cn  = (float)xdbl[r * 160 + 144 + n];
    const float dA  = __expf(dlt * An);
    h = dA * h + (dlt * uu) * Bn;
    float yp = h * Cn;
    yp += __shfl_xor(yp, 1);
    yp += __shfl_xor(yp, 2);
    yp += __shfl_xor(yp, 4);
    yp += __shfl_xor(yp, 8);
    if (n == 0) {
      const float y  = yp + uu * Dd;
      const float rr = (float)res[r * D_INNER + d];
      const float sil = rr / (1.f + __expf(-rr));
      yg[r * D_INNER + d] = (f16)(y * sil);
    }
  }
}

// ---------------- launch ----------------------------------------------------
extern "C" void kernel_launch(void* const* d_in, const int* in_sizes, int n_in,
                              void* d_out, int out_size, void* d_ws, size_t ws_size,
                              hipStream_t stream) {
  const float* x      = (const float*)d_in[0];
  const float* w_in_f = (const float*)d_in[1];
  const float* b_in   = (const float*)d_in[2];
  const float* conv_w = (const float*)d_in[3];
  const float* conv_b = (const float*)d_in[4];
  const float* w_xp_f = (const float*)d_in[5];
  const float* w_dt_f = (const float*)d_in[6];
  const float* b_dt   = (const float*)d_in[7];
  const float* A_log  = (const float*)d_in[8];
  const float* Dp     = (const float*)d_in[9];
  const float* w_ot_f = (const float*)d_in[10];
  const float* b_ot   = (const float*)d_in[11];

  char* ws = (char*)d_ws;
  size_t o = 0;
  auto alloc = [&](size_t bytes) -> char* {
    char* p = ws + o; o += (bytes + 255) & ~(size_t)255; return p;
  };
  f16* xf    = (f16*)alloc(16777216);   // x in f16           [8192][1024]
  f16* w_in  = (f16*)alloc(8388608);    // in_proj_w f16      [4096][1024]
  f16* w_xp  = (f16*)alloc(1048576);    // x_proj_w padded    [256][2048]
  f16* w_dt  = (f16*)alloc(524288);     // dt_proj_w f16      [2048][128]
  f16* w_ot  = (f16*)alloc(4194304);    // out_proj_w f16     [1024][2048]
  f16* xcr   = (f16*)alloc(33554432);   // xc_raw; reused as y_gated
  f16* res   = (f16*)alloc(33554432);   // res gate           [8192][2048]
  f16* xc    = (f16*)alloc(33554432);   // post-conv          [8192][2048]
  f16* xdbl  = (f16*)alloc(2621440);    // x_dbl              [8192][160]
  f16* delta = (f16*)alloc(33554432);   // softplus output    [8192][2048]

  dim3 blk(256);
  cvt_f32_to_f16<<<8192, blk, 0, stream>>>(x,      xf,   2097152);
  cvt_f32_to_f16<<<4096, blk, 0, stream>>>(w_in_f, w_in, 1048576);
  cvt_pad_xproj <<<512,  blk, 0, stream>>>(w_xp_f, w_xp);
  cvt_f32_to_f16<<<256,  blk, 0, stream>>>(w_dt_f, w_dt, 65536);
  cvt_f32_to_f16<<<2048, blk, 0, stream>>>(w_ot_f, w_ot, 524288);

  // in_proj: [8192,1024] @ [4096,1024]^T -> split xc_raw / res
  gemm_f16<0><<<dim3(32, 64), blk, 0, stream>>>(xf, 1024, w_in, 1024, b_in,
                                                xcr, res, 4096, 2048);
  // depthwise conv
  conv1d_kernel<<<1024, blk, 0, stream>>>(xcr, conv_w, conv_b, xc);
  // x_proj: [8192,2048] @ [160(pad 256),2048]^T -> xdbl (ld 160)
  gemm_f16<1><<<dim3(2, 64), blk, 0, stream>>>(xc, 2048, w_xp, 2048, nullptr,
                                               xdbl, nullptr, 160, 160);
  // dt_proj: [8192,128](ld 160) @ [2048,128]^T + b -> softplus -> delta
  gemm_f16<2><<<dim3(16, 64), blk, 0, stream>>>(xdbl, 160, w_dt, 128, b_dt,
                                                delta, nullptr, 2048, 2048);
  // selective scan + u*D + silu(res) gating -> y_gated (reuse xcr)
  scan_kernel<<<512, blk, 0, stream>>>(delta, xc, xdbl, res, A_log, Dp, xcr);
  // out_proj: [8192,2048] @ [1024,2048]^T + b -> d_out f32
  gemm_f16<3><<<dim3(8, 64), blk, 0, stream>>>(xcr, 2048, w_ot, 2048, b_ot,
                                               d_out, nullptr, 1024, 1024);
}

// Round 5
// 513.442 us; speedup vs baseline: 3.6514x; 3.6460x over previous
//
#include <hip/hip_runtime.h>
#include <hip/hip_bf16.h>
#include <hip/hip_fp16.h>

// FastMambaBlock: in_proj GEMM -> split -> depthwise conv1d -> x_proj GEMM
// -> dt_proj GEMM + softplus -> chunked selective scan (pass1/combine/pass2,
// + u*D, silu gating) -> out_proj GEMM. GEMMs: f16 MFMA 16x16x32, 128x128
// tile, BK=32, global_load_lds staging (m97 structure).

typedef _Float16 f16;
typedef __attribute__((ext_vector_type(4))) float f32x4;
typedef __attribute__((ext_vector_type(4))) _Float16 f16x4;
typedef __attribute__((ext_vector_type(8))) _Float16 f16x8;

#define AS1C(p) ((const __attribute__((address_space(1))) void*)(p))
#define AS3(p)  ((__attribute__((address_space(3))) void*)(p))

#define D_MODEL 1024
#define D_INNER 2048
#define LSEQ    2048
#define NB      4
#define NCH     16
#define CLEN    128   // LSEQ / NCH

// ---------------- conversion kernels ----------------
__global__ void cvt_f32_to_f16(const float* __restrict__ in, f16* __restrict__ out, int n4) {
  int i = blockIdx.x * blockDim.x + threadIdx.x;
  if (i >= n4) return;
  f32x4 v = *(const f32x4*)(in + (size_t)i * 4);
  f16x4 o;
  o[0] = (f16)v[0]; o[1] = (f16)v[1]; o[2] = (f16)v[2]; o[3] = (f16)v[3];
  *(f16x4*)(out + (size_t)i * 4) = o;
}

// x_proj_w [160][2048] f32 -> padded [256][2048] f16 (rows 160..255 = 0)
__global__ void cvt_pad_xproj(const float* __restrict__ in, f16* __restrict__ out) {
  int i = blockIdx.x * blockDim.x + threadIdx.x;  // one per 4 elems; total 131072
  int idx = i << 2;
  int row = idx >> 11;
  f16x4 o;
  if (row < 160) {
    f32x4 v = *(const f32x4*)(in + idx);
    o[0] = (f16)v[0]; o[1] = (f16)v[1]; o[2] = (f16)v[2]; o[3] = (f16)v[3];
  } else {
    o[0] = (f16)0.f; o[1] = (f16)0.f; o[2] = (f16)0.f; o[3] = (f16)0.f;
  }
  *(f16x4*)(out + idx) = o;
}

// ---------------- GEMM: C[M][N] = A[M][K] @ W[N][K]^T (+bias, epilogue) ----
// EPI 0: +bias, split-store f16 -> O0 (n<2048: xc_raw), O1 (n>=2048: res)
// EPI 1: no bias, f16 store to O0 with ld=ldo, guard n<NV   (x_proj)
// EPI 2: +bias, softplus, f16 store ld=ldo                  (dt_proj)
// EPI 3: +bias, f32 store ld=ldo                            (out_proj)
template<int EPI>
__global__ __launch_bounds__(256) void gemm_f16(
    const f16* __restrict__ A, int lda,
    const f16* __restrict__ Bw, int K,
    const float* __restrict__ bias,
    void* __restrict__ O0, void* __restrict__ O1,
    int NV, int ldo)
{
  __shared__ f16 lA[128 * 32];
  __shared__ f16 lB[128 * 32];
  const int tid  = threadIdx.x;
  const int lane = tid & 63;
  const int wid  = tid >> 6;
  const int wr = wid >> 1, wc = wid & 1;
  const int tm = blockIdx.y * 128, tn = blockIdx.x * 128;

  f32x4 acc[4][4] = {};

  // staging: 8 chunks of 1KB per tile; wave stages chunks {2*wid, 2*wid+1}
  const int i4 = lane >> 2;          // row within chunk (0..15)
  const int k8 = (lane & 3) << 3;    // k offset (f16 elems)
  const int ca = wid << 1;
  const f16* Abase = A  + (size_t)(tm + ca * 16 + i4) * lda + k8;
  const f16* Bbase = Bw + (size_t)(tn + ca * 16 + i4) * K   + k8;

  const int nKT = K >> 5;
  for (int kt = 0; kt < nKT; ++kt) {
    const int ko = kt << 5;
    __syncthreads();  // previous tile fully consumed
    __builtin_amdgcn_global_load_lds(AS1C(Abase + ko),                    AS3(lA + ca * 512),       16, 0, 0);
    __builtin_amdgcn_global_load_lds(AS1C(Abase + (size_t)16 * lda + ko), AS3(lA + ca * 512 + 512), 16, 0, 0);
    __builtin_amdgcn_global_load_lds(AS1C(Bbase + ko),                    AS3(lB + ca * 512),       16, 0, 0);
    __builtin_amdgcn_global_load_lds(AS1C(Bbase + (size_t)16 * K + ko),   AS3(lB + ca * 512 + 512), 16, 0, 0);
    __syncthreads();  // implies s_waitcnt vmcnt(0) -> staging complete

    const int ro = lane & 15;
    const int kf = (lane >> 4) << 3;  // k-group of 8 per 16-lane group
    f16x8 af[4], bf[4];
#pragma unroll
    for (int mi = 0; mi < 4; ++mi)
      af[mi] = *(const f16x8*)(lA + (wr * 64 + mi * 16 + ro) * 32 + kf);
#pragma unroll
    for (int nj = 0; nj < 4; ++nj)
      bf[nj] = *(const f16x8*)(lB + (wc * 64 + nj * 16 + ro) * 32 + kf);
#pragma unroll
    for (int mi = 0; mi < 4; ++mi)
#pragma unroll
      for (int nj = 0; nj < 4; ++nj)
        acc[mi][nj] = __builtin_amdgcn_mfma_f32_16x16x32_f16(af[mi], bf[nj], acc[mi][nj], 0, 0, 0);
  }

  // epilogue: D row = (lane>>4)*4 + j, col = lane&15
#pragma unroll
  for (int mi = 0; mi < 4; ++mi) {
    const int rb = tm + wr * 64 + mi * 16 + ((lane >> 4) << 2);
#pragma unroll
    for (int nj = 0; nj < 4; ++nj) {
      const int gn = tn + wc * 64 + nj * 16 + (lane & 15);
      if (gn >= NV) continue;
      float bv = 0.f;
      if constexpr (EPI != 1) bv = bias[gn];
#pragma unroll
      for (int j = 0; j < 4; ++j) {
        const float v = acc[mi][nj][j] + bv;
        const size_t row = (size_t)(rb + j);
        if constexpr (EPI == 0) {
          if (gn < 2048) ((f16*)O0)[row * 2048 + gn] = (f16)v;
          else           ((f16*)O1)[row * 2048 + (gn - 2048)] = (f16)v;
        } else if constexpr (EPI == 1) {
          ((f16*)O0)[row * (size_t)ldo + gn] = (f16)v;
        } else if constexpr (EPI == 2) {
          const float sp = (v > 20.f) ? v : log1pf(__expf(v));
          ((f16*)O0)[row * (size_t)ldo + gn] = (f16)sp;
        } else {
          ((float*)O0)[row * (size_t)ldo + gn] = v;
        }
      }
    }
  }
}

// ---------------- depthwise conv1d (k=4, pad 1 left / 2 right) ------------
__global__ __launch_bounds__(256) void conv1d_kernel(
    const f16* __restrict__ xin, const float* __restrict__ w,
    const float* __restrict__ cb, f16* __restrict__ xout)
{
  const int d0  = threadIdx.x << 3;        // 8 channels per thread
  const int bid = blockIdx.x;
  const int b   = bid >> 8;                // 256 blocks per batch
  const int l0  = (bid & 255) << 3;        // 8 timesteps per block
  float wv[4][8];
#pragma unroll
  for (int q = 0; q < 8; ++q) {
    f32x4 t = *(const f32x4*)(w + (size_t)(d0 + q) * 4);
    wv[0][q] = t[0]; wv[1][q] = t[1]; wv[2][q] = t[2]; wv[3][q] = t[3];
  }
  float bv[8];
  *(f32x4*)bv       = *(const f32x4*)(cb + d0);
  *(f32x4*)(bv + 4) = *(const f32x4*)(cb + d0 + 4);
  const size_t base = (size_t)b * LSEQ * D_INNER;
  for (int lt = l0; lt < l0 + 8; ++lt) {
    float acc[8];
#pragma unroll
    for (int q = 0; q < 8; ++q) acc[q] = bv[q];
#pragma unroll
    for (int j = 0; j < 4; ++j) {
      const int li = lt + j - 1;
      if (li < 0 || li >= LSEQ) continue;
      f16x8 v = *(const f16x8*)(xin + base + (size_t)li * D_INNER + d0);
#pragma unroll
      for (int q = 0; q < 8; ++q) acc[q] += wv[j][q] * (float)v[q];
    }
    f16x8 o;
#pragma unroll
    for (int q = 0; q < 8; ++q) o[q] = (f16)acc[q];
    *(f16x8*)(xout + base + (size_t)lt * D_INNER + d0) = o;
  }
}

// ---------------- chunked selective scan ----------------------------------
// Linear recurrence h_t = dA_t h_{t-1} + dBu_t split into NCH chunks of CLEN.
// pass1: per (b, chunk, d) lane holds all 16 n-states; computes chunk-local
//        end state (h0=0) and P = prod dA over chunk.
// combine: per (b,d,n) serial scan over 16 chunks -> entry state per chunk
//          (written in place into chunkH).
// pass2: re-run chunk from its entry state, y = sum_n h*C + u*D, silu gate.

__global__ __launch_bounds__(256) void scan_pass1(
    const f16* __restrict__ delta, const f16* __restrict__ u,
    const f16* __restrict__ xdbl, const float* __restrict__ A_log,
    float* __restrict__ chunkP, float* __restrict__ chunkH)
{
  const int tid = threadIdx.x;
  const int d = blockIdx.x * 256 + tid;
  const int c = blockIdx.y;
  const int b = blockIdx.z;
  __shared__ float bl[CLEN][16];
  // stage B rows (xdbl cols 128..143) -> bl, f32
#pragma unroll
  for (int rep = 0; rep < 2; ++rep) {
    const int j = tid + rep * 256;
    const int t = j >> 2, q = j & 3;
    if (q < 2) {
      f16x8 v = *(const f16x8*)(xdbl + ((size_t)(b * LSEQ + c * CLEN + t)) * 160 + 128 + q * 8);
      float* dst = &bl[t][q * 8];
#pragma unroll
      for (int e = 0; e < 8; ++e) dst[e] = (float)v[e];
    }
  }
  __syncthreads();

  float An[16], h[16], P[16];
  const float* alp = A_log + (size_t)d * 16;
#pragma unroll
  for (int n = 0; n < 16; ++n) { An[n] = -__expf(alp[n]); h[n] = 0.f; P[n] = 1.f; }

  const size_t rbase = ((size_t)(b * LSEQ + c * CLEN)) * D_INNER + d;
  for (int t = 0; t < CLEN; ++t) {
    const size_t off = rbase + (size_t)t * D_INNER;
    const float dlt = (float)delta[off];
    const float uu  = (float)u[off];
    const float du  = dlt * uu;
#pragma unroll
    for (int n = 0; n < 16; ++n) {
      const float dA = __expf(dlt * An[n]);
      h[n] = dA * h[n] + du * bl[t][n];
      P[n] *= dA;
    }
  }
  const size_t ob = (((size_t)b * NCH + c) * D_INNER + d) * 16;
#pragma unroll
  for (int q = 0; q < 4; ++q) {
    f32x4 vp, vh;
#pragma unroll
    for (int j = 0; j < 4; ++j) { vp[j] = P[q * 4 + j]; vh[j] = h[q * 4 + j]; }
    *(f32x4*)(chunkP + ob + q * 4) = vp;
    *(f32x4*)(chunkH + ob + q * 4) = vh;
  }
}

__global__ __launch_bounds__(256) void scan_combine(
    const float* __restrict__ chunkP, float* __restrict__ chunkH)
{
  const int i = blockIdx.x * 256 + threadIdx.x;   // 131072 = 4b * 2048d * 16n
  const int b = i >> 15;
  const int dn = i & 32767;
  const size_t stride = (size_t)D_INNER * 16;
  size_t idx = (size_t)b * NCH * stride + dn;
  float hin = 0.f;
  for (int c = 0; c < NCH; ++c, idx += stride) {
    const float Pv = chunkP[idx];
    const float he = chunkH[idx];
    chunkH[idx] = hin;                 // entry state for chunk c
    hin = Pv * hin + he;
  }
}

__global__ __launch_bounds__(256) void scan_pass2(
    const f16* __restrict__ delta, const f16* __restrict__ u,
    const f16* __restrict__ xdbl, const f16* __restrict__ res,
    const float* __restrict__ A_log, const float* __restrict__ Dp,
    const float* __restrict__ chunkH, f16* __restrict__ yg)
{
  const int tid = threadIdx.x;
  const int d = blockIdx.x * 256 + tid;
  const int c = blockIdx.y;
  const int b = blockIdx.z;
  __shared__ float bl[CLEN][16];
  __shared__ float cl[CLEN][16];
#pragma unroll
  for (int rep = 0; rep < 2; ++rep) {
    const int j = tid + rep * 256;
    const int t = j >> 2, q = j & 3;
    f16x8 v = *(const f16x8*)(xdbl + ((size_t)(b * LSEQ + c * CLEN + t)) * 160 + 128 + q * 8);
    float* dst = (q < 2) ? &bl[t][(q & 1) * 8] : &cl[t][(q & 1) * 8];
#pragma unroll
    for (int e = 0; e < 8; ++e) dst[e] = (float)v[e];
  }
  __syncthreads();

  float An[16], h[16];
  const float* alp = A_log + (size_t)d * 16;
#pragma unroll
  for (int n = 0; n < 16; ++n) An[n] = -__expf(alp[n]);
  const size_t hb = (((size_t)b * NCH + c) * D_INNER + d) * 16;
#pragma unroll
  for (int q = 0; q < 4; ++q) {
    f32x4 v = *(const f32x4*)(chunkH + hb + q * 4);
#pragma unroll
    for (int j = 0; j < 4; ++j) h[q * 4 + j] = v[j];
  }
  const float Dd = Dp[d];

  const size_t rbase = ((size_t)(b * LSEQ + c * CLEN)) * D_INNER + d;
  for (int t = 0; t < CLEN; ++t) {
    const size_t off = rbase + (size_t)t * D_INNER;
    const float dlt = (float)delta[off];
    const float uu  = (float)u[off];
    const float du  = dlt * uu;
    float y0 = 0.f, y1 = 0.f, y2 = 0.f, y3 = 0.f;
#pragma unroll
    for (int q = 0; q < 4; ++q) {
      float yp = 0.f;
#pragma unroll
      for (int e = 0; e < 4; ++e) {
        const int n = q * 4 + e;
        const float dA = __expf(dlt * An[n]);
        h[n] = dA * h[n] + du * bl[t][n];
        yp += h[n] * cl[t][n];
      }
      if (q == 0) y0 = yp; else if (q == 1) y1 = yp; else if (q == 2) y2 = yp; else y3 = yp;
    }
    const float y = (y0 + y1) + (y2 + y3) + uu * Dd;
    const float rr = (float)res[off];
    const float sil = rr / (1.f + __expf(-rr));
    yg[off] = (f16)(y * sil);
  }
}

// ---------------- launch ----------------------------------------------------
extern "C" void kernel_launch(void* const* d_in, const int* in_sizes, int n_in,
                              void* d_out, int out_size, void* d_ws, size_t ws_size,
                              hipStream_t stream) {
  const float* x      = (const float*)d_in[0];
  const float* w_in_f = (const float*)d_in[1];
  const float* b_in   = (const float*)d_in[2];
  const float* conv_w = (const float*)d_in[3];
  const float* conv_b = (const float*)d_in[4];
  const float* w_xp_f = (const float*)d_in[5];
  const float* w_dt_f = (const float*)d_in[6];
  const float* b_dt   = (const float*)d_in[7];
  const float* A_log  = (const float*)d_in[8];
  const float* Dp     = (const float*)d_in[9];
  const float* w_ot_f = (const float*)d_in[10];
  const float* b_ot   = (const float*)d_in[11];

  char* ws = (char*)d_ws;
  size_t o = 0;
  auto alloc = [&](size_t bytes) -> char* {
    char* p = ws + o; o += (bytes + 255) & ~(size_t)255; return p;
  };
  f16* xf    = (f16*)alloc(16777216);   // x in f16 [8192][1024]; dead after gemm0 -> chunkP
  f16* w_in  = (f16*)alloc(8388608);    // in_proj_w f16 [4096][1024]; dead after gemm0 -> chunkH
  f16* w_xp  = (f16*)alloc(1048576);    // x_proj_w padded    [256][2048]
  f16* w_dt  = (f16*)alloc(524288);     // dt_proj_w f16      [2048][128]
  f16* w_ot  = (f16*)alloc(4194304);    // out_proj_w f16     [1024][2048]
  f16* xcr   = (f16*)alloc(33554432);   // xc_raw; reused as y_gated
  f16* res   = (f16*)alloc(33554432);   // res gate           [8192][2048]
  f16* xc    = (f16*)alloc(33554432);   // post-conv          [8192][2048]
  f16* xdbl  = (f16*)alloc(2621440);    // x_dbl              [8192][160]
  f16* delta = (f16*)alloc(33554432);   // softplus output    [8192][2048]

  float* chunkP = (float*)xf;           // [4][16][2048][16] f32 = 8 MB (xf is 16 MB)
  float* chunkH = (float*)w_in;         // [4][16][2048][16] f32 = 8 MB (w_in is 8 MB)

  dim3 blk(256);
  cvt_f32_to_f16<<<8192, blk, 0, stream>>>(x,      xf,   2097152);
  cvt_f32_to_f16<<<4096, blk, 0, stream>>>(w_in_f, w_in, 1048576);
  cvt_pad_xproj <<<512,  blk, 0, stream>>>(w_xp_f, w_xp);
  cvt_f32_to_f16<<<256,  blk, 0, stream>>>(w_dt_f, w_dt, 65536);
  cvt_f32_to_f16<<<2048, blk, 0, stream>>>(w_ot_f, w_ot, 524288);

  // in_proj: [8192,1024] @ [4096,1024]^T -> split xc_raw / res
  gemm_f16<0><<<dim3(32, 64), blk, 0, stream>>>(xf, 1024, w_in, 1024, b_in,
                                                xcr, res, 4096, 2048);
  // depthwise conv
  conv1d_kernel<<<1024, blk, 0, stream>>>(xcr, conv_w, conv_b, xc);
  // x_proj: [8192,2048] @ [160(pad 256),2048]^T -> xdbl (ld 160)
  gemm_f16<1><<<dim3(2, 64), blk, 0, stream>>>(xc, 2048, w_xp, 2048, nullptr,
                                               xdbl, nullptr, 160, 160);
  // dt_proj: [8192,128](ld 160) @ [2048,128]^T + b -> softplus -> delta
  gemm_f16<2><<<dim3(16, 64), blk, 0, stream>>>(xdbl, 160, w_dt, 128, b_dt,
                                                delta, nullptr, 2048, 2048);
  // chunked selective scan: pass1 -> combine -> pass2 (yg reuses xcr)
  scan_pass1  <<<dim3(8, NCH, NB), blk, 0, stream>>>(delta, xc, xdbl, A_log,
                                                     chunkP, chunkH);
  scan_combine<<<512, blk, 0, stream>>>(chunkP, chunkH);
  scan_pass2  <<<dim3(8, NCH, NB), blk, 0, stream>>>(delta, xc, xdbl, res,
                                                     A_log, Dp, chunkH, xcr);
  // out_proj: [8192,2048] @ [1024,2048]^T + b -> d_out f32
  gemm_f16<3><<<dim3(8, 64), blk, 0, stream>>>(xcr, 2048, w_ot, 2048, b_ot,
                                               d_out, nullptr, 1024, 1024);
}

// Round 6
// 429.538 us; speedup vs baseline: 4.3646x; 1.1953x over previous
//
#include <hip/hip_runtime.h>
#include <hip/hip_bf16.h>
#include <hip/hip_fp16.h>

// FastMambaBlock: in_proj GEMM -> split -> depthwise conv1d -> x_proj GEMM
// -> dt_proj GEMM + softplus -> chunked selective scan (pass1/combine/pass2,
// + u*D, silu gating) -> out_proj GEMM. GEMMs: f16 MFMA 16x16x32, 128x128
// tile, BK=32, global_load_lds staging (m97 structure).
// Scan: NCH=32 chunks of CLEN=64 (4 waves/SIMD), state = chunkH [b][c][d][16]
// f32 (aliased on dead xf) + per-chunk delta-sum (aliased on dead w_in);
// decay products reconstructed in combine via exp2(An2 * sum_delta).

typedef _Float16 f16;
typedef __attribute__((ext_vector_type(4))) float f32x4;
typedef __attribute__((ext_vector_type(4))) _Float16 f16x4;
typedef __attribute__((ext_vector_type(8))) _Float16 f16x8;

#define AS1C(p) ((const __attribute__((address_space(1))) void*)(p))
#define AS3(p)  ((__attribute__((address_space(3))) void*)(p))

#define D_MODEL 1024
#define D_INNER 2048
#define LSEQ    2048
#define NB      4
#define NCH     32
#define CLEN    64    // LSEQ / NCH
#define LOG2E   1.44269504f

// ---------------- conversion kernels ----------------
__global__ void cvt_f32_to_f16(const float* __restrict__ in, f16* __restrict__ out, int n4) {
  int i = blockIdx.x * blockDim.x + threadIdx.x;
  if (i >= n4) return;
  f32x4 v = *(const f32x4*)(in + (size_t)i * 4);
  f16x4 o;
  o[0] = (f16)v[0]; o[1] = (f16)v[1]; o[2] = (f16)v[2]; o[3] = (f16)v[3];
  *(f16x4*)(out + (size_t)i * 4) = o;
}

// x_proj_w [160][2048] f32 -> padded [256][2048] f16 (rows 160..255 = 0)
__global__ void cvt_pad_xproj(const float* __restrict__ in, f16* __restrict__ out) {
  int i = blockIdx.x * blockDim.x + threadIdx.x;  // one per 4 elems; total 131072
  int idx = i << 2;
  int row = idx >> 11;
  f16x4 o;
  if (row < 160) {
    f32x4 v = *(const f32x4*)(in + idx);
    o[0] = (f16)v[0]; o[1] = (f16)v[1]; o[2] = (f16)v[2]; o[3] = (f16)v[3];
  } else {
    o[0] = (f16)0.f; o[1] = (f16)0.f; o[2] = (f16)0.f; o[3] = (f16)0.f;
  }
  *(f16x4*)(out + idx) = o;
}

// ---------------- GEMM: C[M][N] = A[M][K] @ W[N][K]^T (+bias, epilogue) ----
// EPI 0: +bias, split-store f16 -> O0 (n<2048: xc_raw), O1 (n>=2048: res)
// EPI 1: no bias, f16 store to O0 with ld=ldo, guard n<NV   (x_proj)
// EPI 2: +bias, softplus, f16 store ld=ldo                  (dt_proj)
// EPI 3: +bias, f32 store ld=ldo                            (out_proj)
template<int EPI>
__global__ __launch_bounds__(256) void gemm_f16(
    const f16* __restrict__ A, int lda,
    const f16* __restrict__ Bw, int K,
    const float* __restrict__ bias,
    void* __restrict__ O0, void* __restrict__ O1,
    int NV, int ldo)
{
  __shared__ f16 lA[128 * 32];
  __shared__ f16 lB[128 * 32];
  const int tid  = threadIdx.x;
  const int lane = tid & 63;
  const int wid  = tid >> 6;
  const int wr = wid >> 1, wc = wid & 1;
  const int tm = blockIdx.y * 128, tn = blockIdx.x * 128;

  f32x4 acc[4][4] = {};

  // staging: 8 chunks of 1KB per tile; wave stages chunks {2*wid, 2*wid+1}
  const int i4 = lane >> 2;          // row within chunk (0..15)
  const int k8 = (lane & 3) << 3;    // k offset (f16 elems)
  const int ca = wid << 1;
  const f16* Abase = A  + (size_t)(tm + ca * 16 + i4) * lda + k8;
  const f16* Bbase = Bw + (size_t)(tn + ca * 16 + i4) * K   + k8;

  const int nKT = K >> 5;
  for (int kt = 0; kt < nKT; ++kt) {
    const int ko = kt << 5;
    __syncthreads();  // previous tile fully consumed
    __builtin_amdgcn_global_load_lds(AS1C(Abase + ko),                    AS3(lA + ca * 512),       16, 0, 0);
    __builtin_amdgcn_global_load_lds(AS1C(Abase + (size_t)16 * lda + ko), AS3(lA + ca * 512 + 512), 16, 0, 0);
    __builtin_amdgcn_global_load_lds(AS1C(Bbase + ko),                    AS3(lB + ca * 512),       16, 0, 0);
    __builtin_amdgcn_global_load_lds(AS1C(Bbase + (size_t)16 * K + ko),   AS3(lB + ca * 512 + 512), 16, 0, 0);
    __syncthreads();  // implies s_waitcnt vmcnt(0) -> staging complete

    const int ro = lane & 15;
    const int kf = (lane >> 4) << 3;  // k-group of 8 per 16-lane group
    f16x8 af[4], bf[4];
#pragma unroll
    for (int mi = 0; mi < 4; ++mi)
      af[mi] = *(const f16x8*)(lA + (wr * 64 + mi * 16 + ro) * 32 + kf);
#pragma unroll
    for (int nj = 0; nj < 4; ++nj)
      bf[nj] = *(const f16x8*)(lB + (wc * 64 + nj * 16 + ro) * 32 + kf);
#pragma unroll
    for (int mi = 0; mi < 4; ++mi)
#pragma unroll
      for (int nj = 0; nj < 4; ++nj)
        acc[mi][nj] = __builtin_amdgcn_mfma_f32_16x16x32_f16(af[mi], bf[nj], acc[mi][nj], 0, 0, 0);
  }

  // epilogue: D row = (lane>>4)*4 + j, col = lane&15
#pragma unroll
  for (int mi = 0; mi < 4; ++mi) {
    const int rb = tm + wr * 64 + mi * 16 + ((lane >> 4) << 2);
#pragma unroll
    for (int nj = 0; nj < 4; ++nj) {
      const int gn = tn + wc * 64 + nj * 16 + (lane & 15);
      if (gn >= NV) continue;
      float bv = 0.f;
      if constexpr (EPI != 1) bv = bias[gn];
#pragma unroll
      for (int j = 0; j < 4; ++j) {
        const float v = acc[mi][nj][j] + bv;
        const size_t row = (size_t)(rb + j);
        if constexpr (EPI == 0) {
          if (gn < 2048) ((f16*)O0)[row * 2048 + gn] = (f16)v;
          else           ((f16*)O1)[row * 2048 + (gn - 2048)] = (f16)v;
        } else if constexpr (EPI == 1) {
          ((f16*)O0)[row * (size_t)ldo + gn] = (f16)v;
        } else if constexpr (EPI == 2) {
          const float sp = (v > 20.f) ? v : log1pf(__expf(v));
          ((f16*)O0)[row * (size_t)ldo + gn] = (f16)sp;
        } else {
          ((float*)O0)[row * (size_t)ldo + gn] = v;
        }
      }
    }
  }
}

// ---------------- depthwise conv1d (k=4, pad 1 left / 2 right) ------------
__global__ __launch_bounds__(256) void conv1d_kernel(
    const f16* __restrict__ xin, const float* __restrict__ w,
    const float* __restrict__ cb, f16* __restrict__ xout)
{
  const int d0  = threadIdx.x << 3;        // 8 channels per thread
  const int bid = blockIdx.x;
  const int b   = bid >> 8;                // 256 blocks per batch
  const int l0  = (bid & 255) << 3;        // 8 timesteps per block
  float wv[4][8];
#pragma unroll
  for (int q = 0; q < 8; ++q) {
    f32x4 t = *(const f32x4*)(w + (size_t)(d0 + q) * 4);
    wv[0][q] = t[0]; wv[1][q] = t[1]; wv[2][q] = t[2]; wv[3][q] = t[3];
  }
  float bv[8];
  *(f32x4*)bv       = *(const f32x4*)(cb + d0);
  *(f32x4*)(bv + 4) = *(const f32x4*)(cb + d0 + 4);
  const size_t base = (size_t)b * LSEQ * D_INNER;
  for (int lt = l0; lt < l0 + 8; ++lt) {
    float acc[8];
#pragma unroll
    for (int q = 0; q < 8; ++q) acc[q] = bv[q];
#pragma unroll
    for (int j = 0; j < 4; ++j) {
      const int li = lt + j - 1;
      if (li < 0 || li >= LSEQ) continue;
      f16x8 v = *(const f16x8*)(xin + base + (size_t)li * D_INNER + d0);
#pragma unroll
      for (int q = 0; q < 8; ++q) acc[q] += wv[j][q] * (float)v[q];
    }
    f16x8 o;
#pragma unroll
    for (int q = 0; q < 8; ++q) o[q] = (f16)acc[q];
    *(f16x8*)(xout + base + (size_t)lt * D_INNER + d0) = o;
  }
}

// ---------------- chunked selective scan ----------------------------------
// h_t = dA_t h_{t-1} + dBu_t, split into NCH chunks of CLEN.
// pass1: per (b,c,d) lane: chunk-local end state (h0=0) + sum of delta.
// combine: per (b,d,n): P_c = exp2(An2 * dsum_c); serial scan over chunks;
//          writes entry state per chunk in place into chunkH.
// pass2: re-run chunk from entry state; y = sum_n h*C + u*D; silu gate.

__global__ __launch_bounds__(256) void scan_pass1(
    const f16* __restrict__ delta, const f16* __restrict__ u,
    const f16* __restrict__ xdbl, const float* __restrict__ A_log,
    float* __restrict__ chunkS, float* __restrict__ chunkH)
{
  const int tid = threadIdx.x;
  const int d = blockIdx.x * 256 + tid;
  const int c = blockIdx.y;
  const int b = blockIdx.z;
  __shared__ float bl[CLEN][16];
  // stage B rows (xdbl cols 128..143) -> bl, f32. CLEN*4 == 256 == blockDim.
  {
    const int t = tid >> 2, q = tid & 3;
    if (q < 2) {
      f16x8 v = *(const f16x8*)(xdbl + ((size_t)(b * LSEQ + c * CLEN + t)) * 160 + 128 + q * 8);
      float* dst = &bl[t][q * 8];
#pragma unroll
      for (int e = 0; e < 8; ++e) dst[e] = (float)v[e];
    }
  }
  __syncthreads();

  float An2[16], h[16];
  const float* alp = A_log + (size_t)d * 16;
#pragma unroll
  for (int n = 0; n < 16; ++n) { An2[n] = -__expf(alp[n]) * LOG2E; h[n] = 0.f; }

  float dsum = 0.f;
  size_t off = ((size_t)(b * LSEQ + c * CLEN)) * D_INNER + d;
  float dlt = (float)delta[off];
  float uu  = (float)u[off];
  for (int t = 0; t < CLEN; ++t) {
    float ndlt = 0.f, nuu = 0.f;
    const size_t noff = off + D_INNER;
    if (t < CLEN - 1) { ndlt = (float)delta[noff]; nuu = (float)u[noff]; }
    const float du = dlt * uu;
    dsum += dlt;
#pragma unroll
    for (int n = 0; n < 16; ++n) {
      const float dA = __builtin_amdgcn_exp2f(An2[n] * dlt);
      h[n] = dA * h[n] + du * bl[t][n];
    }
    dlt = ndlt; uu = nuu; off = noff;
  }
  const size_t sb = ((size_t)b * NCH + c) * D_INNER + d;
  chunkS[sb] = dsum;
  const size_t ob = sb * 16;
#pragma unroll
  for (int q = 0; q < 4; ++q) {
    f32x4 vh;
#pragma unroll
    for (int j = 0; j < 4; ++j) vh[j] = h[q * 4 + j];
    *(f32x4*)(chunkH + ob + q * 4) = vh;
  }
}

__global__ __launch_bounds__(256) void scan_combine(
    const float* __restrict__ chunkS, const float* __restrict__ A_log,
    float* __restrict__ chunkH)
{
  const int i = blockIdx.x * 256 + threadIdx.x;   // 131072 = 4b * 2048d * 16n
  const int b = i >> 15;
  const int dn = i & 32767;                        // d*16 + n
  const int d = dn >> 4;
  const float An2 = -__expf(A_log[dn]) * LOG2E;
  const size_t hstride = (size_t)D_INNER * 16;
  size_t sIdx = (size_t)b * NCH * D_INNER + d;
  size_t hIdx = ((size_t)b * NCH * D_INNER) * 16 + dn;
  float hin = 0.f;
  for (int c = 0; c < NCH; ++c) {
    const float P  = __builtin_amdgcn_exp2f(An2 * chunkS[sIdx]);
    const float he = chunkH[hIdx];
    chunkH[hIdx] = hin;                 // entry state for chunk c
    hin = P * hin + he;
    sIdx += D_INNER; hIdx += hstride;
  }
}

__global__ __launch_bounds__(256) void scan_pass2(
    const f16* __restrict__ delta, const f16* __restrict__ u,
    const f16* __restrict__ xdbl, const f16* __restrict__ res,
    const float* __restrict__ A_log, const float* __restrict__ Dp,
    const float* __restrict__ chunkH, f16* __restrict__ yg)
{
  const int tid = threadIdx.x;
  const int d = blockIdx.x * 256 + tid;
  const int c = blockIdx.y;
  const int b = blockIdx.z;
  __shared__ float bl[CLEN][16];
  __shared__ float cl[CLEN][16];
  // stage B and C rows. CLEN*4 == 256 == blockDim.
  {
    const int t = tid >> 2, q = tid & 3;
    f16x8 v = *(const f16x8*)(xdbl + ((size_t)(b * LSEQ + c * CLEN + t)) * 160 + 128 + q * 8);
    float* dst = (q < 2) ? &bl[t][(q & 1) * 8] : &cl[t][(q & 1) * 8];
#pragma unroll
    for (int e = 0; e < 8; ++e) dst[e] = (float)v[e];
  }
  __syncthreads();

  float An2[16], h[16];
  const float* alp = A_log + (size_t)d * 16;
#pragma unroll
  for (int n = 0; n < 16; ++n) An2[n] = -__expf(alp[n]) * LOG2E;
  const size_t hb = (((size_t)b * NCH + c) * D_INNER + d) * 16;
#pragma unroll
  for (int q = 0; q < 4; ++q) {
    f32x4 v = *(const f32x4*)(chunkH + hb + q * 4);
#pragma unroll
    for (int j = 0; j < 4; ++j) h[q * 4 + j] = v[j];
  }
  const float Dd = Dp[d];

  size_t off = ((size_t)(b * LSEQ + c * CLEN)) * D_INNER + d;
  float dlt = (float)delta[off];
  float uu  = (float)u[off];
  float rr  = (float)res[off];
  for (int t = 0; t < CLEN; ++t) {
    float ndlt = 0.f, nuu = 0.f, nrr = 0.f;
    const size_t noff = off + D_INNER;
    if (t < CLEN - 1) {
      ndlt = (float)delta[noff]; nuu = (float)u[noff]; nrr = (float)res[noff];
    }
    const float du = dlt * uu;
    float y0 = 0.f, y1 = 0.f, y2 = 0.f, y3 = 0.f;
#pragma unroll
    for (int q = 0; q < 4; ++q) {
      float yp = 0.f;
#pragma unroll
      for (int e = 0; e < 4; ++e) {
        const int n = q * 4 + e;
        const float dA = __builtin_amdgcn_exp2f(An2[n] * dlt);
        h[n] = dA * h[n] + du * bl[t][n];
        yp += h[n] * cl[t][n];
      }
      if (q == 0) y0 = yp; else if (q == 1) y1 = yp; else if (q == 2) y2 = yp; else y3 = yp;
    }
    const float y = (y0 + y1) + (y2 + y3) + uu * Dd;
    const float sil = rr / (1.f + __expf(-rr));
    yg[off] = (f16)(y * sil);
    dlt = ndlt; uu = nuu; rr = nrr; off = noff;
  }
}

// ---------------- launch ----------------------------------------------------
extern "C" void kernel_launch(void* const* d_in, const int* in_sizes, int n_in,
                              void* d_out, int out_size, void* d_ws, size_t ws_size,
                              hipStream_t stream) {
  const float* x      = (const float*)d_in[0];
  const float* w_in_f = (const float*)d_in[1];
  const float* b_in   = (const float*)d_in[2];
  const float* conv_w = (const float*)d_in[3];
  const float* conv_b = (const float*)d_in[4];
  const float* w_xp_f = (const float*)d_in[5];
  const float* w_dt_f = (const float*)d_in[6];
  const float* b_dt   = (const float*)d_in[7];
  const float* A_log  = (const float*)d_in[8];
  const float* Dp     = (const float*)d_in[9];
  const float* w_ot_f = (const float*)d_in[10];
  const float* b_ot   = (const float*)d_in[11];

  char* ws = (char*)d_ws;
  size_t o = 0;
  auto alloc = [&](size_t bytes) -> char* {
    char* p = ws + o; o += (bytes + 255) & ~(size_t)255; return p;
  };
  f16* xf    = (f16*)alloc(16777216);   // x in f16 [8192][1024]; dead after gemm0 -> chunkH (16.78MB exact)
  f16* w_in  = (f16*)alloc(8388608);    // in_proj_w f16 [4096][1024]; dead after gemm0 -> chunkS (1MB)
  f16* w_xp  = (f16*)alloc(1048576);    // x_proj_w padded    [256][2048]
  f16* w_dt  = (f16*)alloc(524288);     // dt_proj_w f16      [2048][128]
  f16* w_ot  = (f16*)alloc(4194304);    // out_proj_w f16     [1024][2048]
  f16* xcr   = (f16*)alloc(33554432);   // xc_raw; reused as y_gated
  f16* res   = (f16*)alloc(33554432);   // res gate           [8192][2048]
  f16* xc    = (f16*)alloc(33554432);   // post-conv          [8192][2048]
  f16* xdbl  = (f16*)alloc(2621440);    // x_dbl              [8192][160]
  f16* delta = (f16*)alloc(33554432);   // softplus output    [8192][2048]

  float* chunkH = (float*)xf;           // [4][NCH][2048][16] f32 = 16.78MB (xf is 16.78MB)
  float* chunkS = (float*)w_in;         // [4][NCH][2048]     f32 = 1MB    (w_in is 8.4MB)

  dim3 blk(256);
  cvt_f32_to_f16<<<8192, blk, 0, stream>>>(x,      xf,   2097152);
  cvt_f32_to_f16<<<4096, blk, 0, stream>>>(w_in_f, w_in, 1048576);
  cvt_pad_xproj <<<512,  blk, 0, stream>>>(w_xp_f, w_xp);
  cvt_f32_to_f16<<<256,  blk, 0, stream>>>(w_dt_f, w_dt, 65536);
  cvt_f32_to_f16<<<2048, blk, 0, stream>>>(w_ot_f, w_ot, 524288);

  // in_proj: [8192,1024] @ [4096,1024]^T -> split xc_raw / res
  gemm_f16<0><<<dim3(32, 64), blk, 0, stream>>>(xf, 1024, w_in, 1024, b_in,
                                                xcr, res, 4096, 2048);
  // depthwise conv
  conv1d_kernel<<<1024, blk, 0, stream>>>(xcr, conv_w, conv_b, xc);
  // x_proj: [8192,2048] @ [160(pad 256),2048]^T -> xdbl (ld 160)
  gemm_f16<1><<<dim3(2, 64), blk, 0, stream>>>(xc, 2048, w_xp, 2048, nullptr,
                                               xdbl, nullptr, 160, 160);
  // dt_proj: [8192,128](ld 160) @ [2048,128]^T + b -> softplus -> delta
  gemm_f16<2><<<dim3(16, 64), blk, 0, stream>>>(xdbl, 160, w_dt, 128, b_dt,
                                                delta, nullptr, 2048, 2048);
  // chunked selective scan: pass1 -> combine -> pass2 (yg reuses xcr)
  scan_pass1  <<<dim3(8, NCH, NB), blk, 0, stream>>>(delta, xc, xdbl, A_log,
                                                     chunkS, chunkH);
  scan_combine<<<512, blk, 0, stream>>>(chunkS, A_log, chunkH);
  scan_pass2  <<<dim3(8, NCH, NB), blk, 0, stream>>>(delta, xc, xdbl, res,
                                                     A_log, Dp, chunkH, xcr);
  // out_proj: [8192,2048] @ [1024,2048]^T + b -> d_out f32
  gemm_f16<3><<<dim3(8, 64), blk, 0, stream>>>(xcr, 2048, w_ot, 2048, b_ot,
                                               d_out, nullptr, 1024, 1024);
}

// Round 7
// 419.639 us; speedup vs baseline: 4.4676x; 1.0236x over previous
//
#include <hip/hip_runtime.h>
#include <hip/hip_bf16.h>
#include <hip/hip_fp16.h>

// FastMambaBlock: in_proj GEMM -> split -> depthwise conv1d -> x_proj GEMM
// -> dt_proj GEMM + softplus -> chunked selective scan (pass1/combine/pass2,
// + u*D, silu gating) -> out_proj GEMM. GEMMs: f16 MFMA 16x16x32, 128x128
// tile, BK=32, global_load_lds staging (m97 structure), XCD N-slab swizzle
// on the two big GEMMs. Scan: NCH=32 chunks of CLEN=64, 4-deep t-group
// load pipelining; chunk state aliased on dead xf/w_in buffers.

typedef _Float16 f16;
typedef __attribute__((ext_vector_type(4))) float f32x4;
typedef __attribute__((ext_vector_type(4))) _Float16 f16x4;
typedef __attribute__((ext_vector_type(8))) _Float16 f16x8;

#define AS1C(p) ((const __attribute__((address_space(1))) void*)(p))
#define AS3(p)  ((__attribute__((address_space(3))) void*)(p))

#define D_MODEL 1024
#define D_INNER 2048
#define LSEQ    2048
#define NB      4
#define NCH     32
#define CLEN    64    // LSEQ / NCH
#define LOG2E   1.44269504f

// ---------------- conversion kernels ----------------
__global__ void cvt_f32_to_f16(const float* __restrict__ in, f16* __restrict__ out, int n4) {
  int i = blockIdx.x * blockDim.x + threadIdx.x;
  if (i >= n4) return;
  f32x4 v = *(const f32x4*)(in + (size_t)i * 4);
  f16x4 o;
  o[0] = (f16)v[0]; o[1] = (f16)v[1]; o[2] = (f16)v[2]; o[3] = (f16)v[3];
  *(f16x4*)(out + (size_t)i * 4) = o;
}

// x_proj_w [160][2048] f32 -> padded [256][2048] f16 (rows 160..255 = 0)
__global__ void cvt_pad_xproj(const float* __restrict__ in, f16* __restrict__ out) {
  int i = blockIdx.x * blockDim.x + threadIdx.x;  // one per 4 elems; total 131072
  int idx = i << 2;
  int row = idx >> 11;
  f16x4 o;
  if (row < 160) {
    f32x4 v = *(const f32x4*)(in + idx);
    o[0] = (f16)v[0]; o[1] = (f16)v[1]; o[2] = (f16)v[2]; o[3] = (f16)v[3];
  } else {
    o[0] = (f16)0.f; o[1] = (f16)0.f; o[2] = (f16)0.f; o[3] = (f16)0.f;
  }
  *(f16x4*)(out + idx) = o;
}

// ---------------- GEMM: C[M][N] = A[M][K] @ W[N][K]^T (+bias, epilogue) ----
// 1-D grid of gx*gy blocks. XSW: XCD N-slab swizzle (requires gx*gy % 8 == 0,
// gx % 8 == 0 or gx >= 8 with nxs = gx/8 >= 1): each XCD owns a contiguous
// slab of N-tiles so its B-panels stay L2-resident.
// EPI 0: +bias, split-store f16 -> O0 (n<2048: xc_raw), O1 (n>=2048: res)
// EPI 1: no bias, f16 store to O0 with ld=ldo, guard n<NV   (x_proj)
// EPI 2: +bias, softplus, f16 store ld=ldo                  (dt_proj)
// EPI 3: +bias, f32 store ld=ldo                            (out_proj)
template<int EPI, bool XSW>
__global__ __launch_bounds__(256) void gemm_f16(
    const f16* __restrict__ A, int lda,
    const f16* __restrict__ Bw, int K,
    const float* __restrict__ bias,
    void* __restrict__ O0, void* __restrict__ O1,
    int NV, int ldo, int gx)
{
  __shared__ f16 lA[128 * 32];
  __shared__ f16 lB[128 * 32];
  const int tid  = threadIdx.x;
  const int lane = tid & 63;
  const int wid  = tid >> 6;
  const int wr = wid >> 1, wc = wid & 1;

  int tn_i, tm_i;
  {
    const int bid = blockIdx.x;
    if constexpr (XSW) {
      const int nxs = gx >> 3;        // N-tiles per XCD slab
      const int xcd = bid & 7;
      const int j   = bid >> 3;
      tn_i = xcd * nxs + j % nxs;
      tm_i = j / nxs;
    } else {
      tn_i = bid % gx;
      tm_i = bid / gx;
    }
  }
  const int tm = tm_i * 128, tn = tn_i * 128;

  f32x4 acc[4][4] = {};

  // staging: 8 chunks of 1KB per tile; wave stages chunks {2*wid, 2*wid+1}
  const int i4 = lane >> 2;          // row within chunk (0..15)
  const int k8 = (lane & 3) << 3;    // k offset (f16 elems)
  const int ca = wid << 1;
  const f16* Abase = A  + (size_t)(tm + ca * 16 + i4) * lda + k8;
  const f16* Bbase = Bw + (size_t)(tn + ca * 16 + i4) * K   + k8;

  const int nKT = K >> 5;
  for (int kt = 0; kt < nKT; ++kt) {
    const int ko = kt << 5;
    __syncthreads();  // previous tile fully consumed
    __builtin_amdgcn_global_load_lds(AS1C(Abase + ko),                    AS3(lA + ca * 512),       16, 0, 0);
    __builtin_amdgcn_global_load_lds(AS1C(Abase + (size_t)16 * lda + ko), AS3(lA + ca * 512 + 512), 16, 0, 0);
    __builtin_amdgcn_global_load_lds(AS1C(Bbase + ko),                    AS3(lB + ca * 512),       16, 0, 0);
    __builtin_amdgcn_global_load_lds(AS1C(Bbase + (size_t)16 * K + ko),   AS3(lB + ca * 512 + 512), 16, 0, 0);
    __syncthreads();  // implies s_waitcnt vmcnt(0) -> staging complete

    const int ro = lane & 15;
    const int kf = (lane >> 4) << 3;  // k-group of 8 per 16-lane group
    f16x8 af[4], bf[4];
#pragma unroll
    for (int mi = 0; mi < 4; ++mi)
      af[mi] = *(const f16x8*)(lA + (wr * 64 + mi * 16 + ro) * 32 + kf);
#pragma unroll
    for (int nj = 0; nj < 4; ++nj)
      bf[nj] = *(const f16x8*)(lB + (wc * 64 + nj * 16 + ro) * 32 + kf);
#pragma unroll
    for (int mi = 0; mi < 4; ++mi)
#pragma unroll
      for (int nj = 0; nj < 4; ++nj)
        acc[mi][nj] = __builtin_amdgcn_mfma_f32_16x16x32_f16(af[mi], bf[nj], acc[mi][nj], 0, 0, 0);
  }

  // epilogue: D row = (lane>>4)*4 + j, col = lane&15
#pragma unroll
  for (int mi = 0; mi < 4; ++mi) {
    const int rb = tm + wr * 64 + mi * 16 + ((lane >> 4) << 2);
#pragma unroll
    for (int nj = 0; nj < 4; ++nj) {
      const int gn = tn + wc * 64 + nj * 16 + (lane & 15);
      if (gn >= NV) continue;
      float bv = 0.f;
      if constexpr (EPI != 1) bv = bias[gn];
#pragma unroll
      for (int j = 0; j < 4; ++j) {
        const float v = acc[mi][nj][j] + bv;
        const size_t row = (size_t)(rb + j);
        if constexpr (EPI == 0) {
          if (gn < 2048) ((f16*)O0)[row * 2048 + gn] = (f16)v;
          else           ((f16*)O1)[row * 2048 + (gn - 2048)] = (f16)v;
        } else if constexpr (EPI == 1) {
          ((f16*)O0)[row * (size_t)ldo + gn] = (f16)v;
        } else if constexpr (EPI == 2) {
          const float sp = (v > 20.f) ? v : log1pf(__expf(v));
          ((f16*)O0)[row * (size_t)ldo + gn] = (f16)sp;
        } else {
          ((float*)O0)[row * (size_t)ldo + gn] = v;
        }
      }
    }
  }
}

// ---------------- depthwise conv1d (k=4, pad 1 left / 2 right) ------------
__global__ __launch_bounds__(256) void conv1d_kernel(
    const f16* __restrict__ xin, const float* __restrict__ w,
    const float* __restrict__ cb, f16* __restrict__ xout)
{
  const int d0  = threadIdx.x << 3;        // 8 channels per thread
  const int bid = blockIdx.x;
  const int b   = bid >> 8;                // 256 blocks per batch
  const int l0  = (bid & 255) << 3;        // 8 timesteps per block
  float wv[4][8];
#pragma unroll
  for (int q = 0; q < 8; ++q) {
    f32x4 t = *(const f32x4*)(w + (size_t)(d0 + q) * 4);
    wv[0][q] = t[0]; wv[1][q] = t[1]; wv[2][q] = t[2]; wv[3][q] = t[3];
  }
  float bv[8];
  *(f32x4*)bv       = *(const f32x4*)(cb + d0);
  *(f32x4*)(bv + 4) = *(const f32x4*)(cb + d0 + 4);
  const size_t base = (size_t)b * LSEQ * D_INNER;
  for (int lt = l0; lt < l0 + 8; ++lt) {
    float acc[8];
#pragma unroll
    for (int q = 0; q < 8; ++q) acc[q] = bv[q];
#pragma unroll
    for (int j = 0; j < 4; ++j) {
      const int li = lt + j - 1;
      if (li < 0 || li >= LSEQ) continue;
      f16x8 v = *(const f16x8*)(xin + base + (size_t)li * D_INNER + d0);
#pragma unroll
      for (int q = 0; q < 8; ++q) acc[q] += wv[j][q] * (float)v[q];
    }
    f16x8 o;
#pragma unroll
    for (int q = 0; q < 8; ++q) o[q] = (f16)acc[q];
    *(f16x8*)(xout + base + (size_t)lt * D_INNER + d0) = o;
  }
}

// ---------------- chunked selective scan ----------------------------------
// h_t = dA_t h_{t-1} + dBu_t, split into NCH chunks of CLEN.
// pass1: per (b,c,d) lane: chunk-local end state (h0=0) + sum of delta.
// combine: per (b,d,n): P_c = exp2(An2 * dsum_c); serial scan over chunks;
//          writes entry state per chunk in place into chunkH.
// pass2: re-run chunk from entry state; y = sum_n h*C + u*D; silu gate.
// Both passes pipeline loads 4 timesteps deep (group-of-4 prefetch).

__global__ __launch_bounds__(256) void scan_pass1(
    const f16* __restrict__ delta, const f16* __restrict__ u,
    const f16* __restrict__ xdbl, const float* __restrict__ A_log,
    float* __restrict__ chunkS, float* __restrict__ chunkH)
{
  const int tid = threadIdx.x;
  const int d = blockIdx.x * 256 + tid;
  const int c = blockIdx.y;
  const int b = blockIdx.z;
  __shared__ float bl[CLEN][16];
  // stage B rows (xdbl cols 128..143) -> bl, f32. CLEN*4 == 256 == blockDim.
  {
    const int t = tid >> 2, q = tid & 3;
    if (q < 2) {
      f16x8 v = *(const f16x8*)(xdbl + ((size_t)(b * LSEQ + c * CLEN + t)) * 160 + 128 + q * 8);
      float* dst = &bl[t][q * 8];
#pragma unroll
      for (int e = 0; e < 8; ++e) dst[e] = (float)v[e];
    }
  }
  __syncthreads();

  float An2[16], h[16];
  const float* alp = A_log + (size_t)d * 16;
#pragma unroll
  for (int n = 0; n < 16; ++n) { An2[n] = -__expf(alp[n]) * LOG2E; h[n] = 0.f; }

  float dsum = 0.f;
  const size_t base = ((size_t)(b * LSEQ + c * CLEN)) * D_INNER + d;
  float dl[4], uu[4];
#pragma unroll
  for (int j = 0; j < 4; ++j) {
    dl[j] = (float)delta[base + (size_t)j * D_INNER];
    uu[j] = (float)u[base + (size_t)j * D_INNER];
  }
  for (int g = 0; g < CLEN / 4; ++g) {
    float ndl[4] = {0.f, 0.f, 0.f, 0.f}, nuu[4] = {0.f, 0.f, 0.f, 0.f};
    if (g < CLEN / 4 - 1) {
      const size_t nb = base + (size_t)(g + 1) * 4 * D_INNER;
#pragma unroll
      for (int j = 0; j < 4; ++j) {
        ndl[j] = (float)delta[nb + (size_t)j * D_INNER];
        nuu[j] = (float)u[nb + (size_t)j * D_INNER];
      }
    }
#pragma unroll
    for (int j = 0; j < 4; ++j) {
      const int t = g * 4 + j;
      const float du = dl[j] * uu[j];
      dsum += dl[j];
#pragma unroll
      for (int n = 0; n < 16; ++n) {
        const float dA = __builtin_amdgcn_exp2f(An2[n] * dl[j]);
        h[n] = dA * h[n] + du * bl[t][n];
      }
    }
#pragma unroll
    for (int j = 0; j < 4; ++j) { dl[j] = ndl[j]; uu[j] = nuu[j]; }
  }
  const size_t sb = ((size_t)b * NCH + c) * D_INNER + d;
  chunkS[sb] = dsum;
  const size_t ob = sb * 16;
#pragma unroll
  for (int q = 0; q < 4; ++q) {
    f32x4 vh;
#pragma unroll
    for (int j = 0; j < 4; ++j) vh[j] = h[q * 4 + j];
    *(f32x4*)(chunkH + ob + q * 4) = vh;
  }
}

__global__ __launch_bounds__(256) void scan_combine(
    const float* __restrict__ chunkS, const float* __restrict__ A_log,
    float* __restrict__ chunkH)
{
  const int i = blockIdx.x * 256 + threadIdx.x;   // 131072 = 4b * 2048d * 16n
  const int b = i >> 15;
  const int dn = i & 32767;                        // d*16 + n
  const int d = dn >> 4;
  const float An2 = -__expf(A_log[dn]) * LOG2E;
  const size_t hstride = (size_t)D_INNER * 16;
  size_t sIdx = (size_t)b * NCH * D_INNER + d;
  size_t hIdx = ((size_t)b * NCH * D_INNER) * 16 + dn;
  float hin = 0.f;
  for (int c = 0; c < NCH; ++c) {
    const float P  = __builtin_amdgcn_exp2f(An2 * chunkS[sIdx]);
    const float he = chunkH[hIdx];
    chunkH[hIdx] = hin;                 // entry state for chunk c
    hin = P * hin + he;
    sIdx += D_INNER; hIdx += hstride;
  }
}

__global__ __launch_bounds__(256) void scan_pass2(
    const f16* __restrict__ delta, const f16* __restrict__ u,
    const f16* __restrict__ xdbl, const f16* __restrict__ res,
    const float* __restrict__ A_log, const float* __restrict__ Dp,
    const float* __restrict__ chunkH, f16* __restrict__ yg)
{
  const int tid = threadIdx.x;
  const int d = blockIdx.x * 256 + tid;
  const int c = blockIdx.y;
  const int b = blockIdx.z;
  __shared__ float bl[CLEN][16];
  __shared__ float cl[CLEN][16];
  // stage B and C rows. CLEN*4 == 256 == blockDim.
  {
    const int t = tid >> 2, q = tid & 3;
    f16x8 v = *(const f16x8*)(xdbl + ((size_t)(b * LSEQ + c * CLEN + t)) * 160 + 128 + q * 8);
    float* dst = (q < 2) ? &bl[t][(q & 1) * 8] : &cl[t][(q & 1) * 8];
#pragma unroll
    for (int e = 0; e < 8; ++e) dst[e] = (float)v[e];
  }
  __syncthreads();

  float An2[16], h[16];
  const float* alp = A_log + (size_t)d * 16;
#pragma unroll
  for (int n = 0; n < 16; ++n) An2[n] = -__expf(alp[n]) * LOG2E;
  const size_t hb = (((size_t)b * NCH + c) * D_INNER + d) * 16;
#pragma unroll
  for (int q = 0; q < 4; ++q) {
    f32x4 v = *(const f32x4*)(chunkH + hb + q * 4);
#pragma unroll
    for (int j = 0; j < 4; ++j) h[q * 4 + j] = v[j];
  }
  const float Dd = Dp[d];

  const size_t base = ((size_t)(b * LSEQ + c * CLEN)) * D_INNER + d;
  float dl[4], uu[4], rr[4];
#pragma unroll
  for (int j = 0; j < 4; ++j) {
    dl[j] = (float)delta[base + (size_t)j * D_INNER];
    uu[j] = (float)u[base + (size_t)j * D_INNER];
    rr[j] = (float)res[base + (size_t)j * D_INNER];
  }
  for (int g = 0; g < CLEN / 4; ++g) {
    float ndl[4] = {0.f, 0.f, 0.f, 0.f}, nuu[4] = {0.f, 0.f, 0.f, 0.f},
          nrr[4] = {0.f, 0.f, 0.f, 0.f};
    if (g < CLEN / 4 - 1) {
      const size_t nb = base + (size_t)(g + 1) * 4 * D_INNER;
#pragma unroll
      for (int j = 0; j < 4; ++j) {
        ndl[j] = (float)delta[nb + (size_t)j * D_INNER];
        nuu[j] = (float)u[nb + (size_t)j * D_INNER];
        nrr[j] = (float)res[nb + (size_t)j * D_INNER];
      }
    }
#pragma unroll
    for (int j = 0; j < 4; ++j) {
      const int t = g * 4 + j;
      const float du = dl[j] * uu[j];
      float y0 = 0.f, y1 = 0.f, y2 = 0.f, y3 = 0.f;
#pragma unroll
      for (int q = 0; q < 4; ++q) {
        float yp = 0.f;
#pragma unroll
        for (int e = 0; e < 4; ++e) {
          const int n = q * 4 + e;
          const float dA = __builtin_amdgcn_exp2f(An2[n] * dl[j]);
          h[n] = dA * h[n] + du * bl[t][n];
          yp += h[n] * cl[t][n];
        }
        if (q == 0) y0 = yp; else if (q == 1) y1 = yp; else if (q == 2) y2 = yp; else y3 = yp;
      }
      const float y = (y0 + y1) + (y2 + y3) + uu[j] * Dd;
      const float sil = rr[j] / (1.f + __expf(-rr[j]));
      yg[base + (size_t)t * D_INNER] = (f16)(y * sil);
    }
#pragma unroll
    for (int j = 0; j < 4; ++j) { dl[j] = ndl[j]; uu[j] = nuu[j]; rr[j] = nrr[j]; }
  }
}

// ---------------- launch ----------------------------------------------------
extern "C" void kernel_launch(void* const* d_in, const int* in_sizes, int n_in,
                              void* d_out, int out_size, void* d_ws, size_t ws_size,
                              hipStream_t stream) {
  const float* x      = (const float*)d_in[0];
  const float* w_in_f = (const float*)d_in[1];
  const float* b_in   = (const float*)d_in[2];
  const float* conv_w = (const float*)d_in[3];
  const float* conv_b = (const float*)d_in[4];
  const float* w_xp_f = (const float*)d_in[5];
  const float* w_dt_f = (const float*)d_in[6];
  const float* b_dt   = (const float*)d_in[7];
  const float* A_log  = (const float*)d_in[8];
  const float* Dp     = (const float*)d_in[9];
  const float* w_ot_f = (const float*)d_in[10];
  const float* b_ot   = (const float*)d_in[11];

  char* ws = (char*)d_ws;
  size_t o = 0;
  auto alloc = [&](size_t bytes) -> char* {
    char* p = ws + o; o += (bytes + 255) & ~(size_t)255; return p;
  };
  f16* xf    = (f16*)alloc(16777216);   // x in f16 [8192][1024]; dead after gemm0 -> chunkH (16.78MB exact)
  f16* w_in  = (f16*)alloc(8388608);    // in_proj_w f16 [4096][1024]; dead after gemm0 -> chunkS (1MB)
  f16* w_xp  = (f16*)alloc(1048576);    // x_proj_w padded    [256][2048]
  f16* w_dt  = (f16*)alloc(524288);     // dt_proj_w f16      [2048][128]
  f16* w_ot  = (f16*)alloc(4194304);    // out_proj_w f16     [1024][2048]
  f16* xcr   = (f16*)alloc(33554432);   // xc_raw; reused as y_gated
  f16* res   = (f16*)alloc(33554432);   // res gate           [8192][2048]
  f16* xc    = (f16*)alloc(33554432);   // post-conv          [8192][2048]
  f16* xdbl  = (f16*)alloc(2621440);    // x_dbl              [8192][160]
  f16* delta = (f16*)alloc(33554432);   // softplus output    [8192][2048]

  float* chunkH = (float*)xf;           // [4][NCH][2048][16] f32 = 16.78MB (xf is 16.78MB)
  float* chunkS = (float*)w_in;         // [4][NCH][2048]     f32 = 1MB    (w_in is 8.4MB)

  dim3 blk(256);
  cvt_f32_to_f16<<<8192, blk, 0, stream>>>(x,      xf,   2097152);
  cvt_f32_to_f16<<<4096, blk, 0, stream>>>(w_in_f, w_in, 1048576);
  cvt_pad_xproj <<<512,  blk, 0, stream>>>(w_xp_f, w_xp);
  cvt_f32_to_f16<<<256,  blk, 0, stream>>>(w_dt_f, w_dt, 65536);
  cvt_f32_to_f16<<<2048, blk, 0, stream>>>(w_ot_f, w_ot, 524288);

  // in_proj: [8192,1024] @ [4096,1024]^T -> split xc_raw / res (XCD slab: 4 N-tiles/XCD)
  gemm_f16<0, true><<<2048, blk, 0, stream>>>(xf, 1024, w_in, 1024, b_in,
                                              xcr, res, 4096, 2048, 32);
  // depthwise conv
  conv1d_kernel<<<1024, blk, 0, stream>>>(xcr, conv_w, conv_b, xc);
  // x_proj: [8192,2048] @ [160(pad 256),2048]^T -> xdbl (ld 160)
  gemm_f16<1, false><<<128, blk, 0, stream>>>(xc, 2048, w_xp, 2048, nullptr,
                                              xdbl, nullptr, 160, 160, 2);
  // dt_proj: [8192,128](ld 160) @ [2048,128]^T + b -> softplus -> delta
  gemm_f16<2, false><<<1024, blk, 0, stream>>>(xdbl, 160, w_dt, 128, b_dt,
                                               delta, nullptr, 2048, 2048, 16);
  // chunked selective scan: pass1 -> combine -> pass2 (yg reuses xcr)
  scan_pass1  <<<dim3(8, NCH, NB), blk, 0, stream>>>(delta, xc, xdbl, A_log,
                                                     chunkS, chunkH);
  scan_combine<<<512, blk, 0, stream>>>(chunkS, A_log, chunkH);
  scan_pass2  <<<dim3(8, NCH, NB), blk, 0, stream>>>(delta, xc, xdbl, res,
                                                     A_log, Dp, chunkH, xcr);
  // out_proj: [8192,2048] @ [1024,2048]^T + b -> d_out f32 (XCD slab: 1 N-tile/XCD)
  gemm_f16<3, true><<<512, blk, 0, stream>>>(xcr, 2048, w_ot, 2048, b_ot,
                                             d_out, nullptr, 1024, 1024, 8);
}